// Round 2
// baseline (6322.476 us; speedup 1.0000x reference)
//
#include <hip/hip_runtime.h>
#include <hip/hip_bf16.h>
#include <math.h>

#define BATCH   8
#define SEQ     1024
#define DMODEL  256
#define NHEADS  8
#define HDIM    256
#define NQKV    2048      /* NHEADS*HDIM */
#define DFF     1024
#define MROWS   (BATCH*SEQ)
#define LN_EPS  1e-3f
#define ATT_SCALE 0.0625f /* 1/sqrt(256) */

// ---------------------------------------------------------------------------
// GEMM: C[M,N-block] = A[M,K] @ W[K,*] + epilogue, with runtime strides.
// EPI: 0 = +bias, 1 = +bias+ReLU, 2 = +bias+resid, 3 = accumulate into C (no bias)
// 128x128 tile, 8x8 microtile, BK=16. Split micro-tile (tx*4 / tx*4+64) for
// coalesced 256B C-writes and 2-way-only LDS bank aliasing (free per m136).
template<int EPI>
__global__ __launch_bounds__(256, 2)
void gemm_f32(const float* __restrict__ A, const float* __restrict__ W,
              const float* __restrict__ bias, const float* __restrict__ resid,
              float* __restrict__ C, int K, int lda, int ldw, int ldc)
{
    constexpr int BM = 128, BN = 128, BK = 16;
    __shared__ float As[BK][BM + 4];   // stored transposed: As[k][m]
    __shared__ float Ws[BK][BN];
    const int t  = threadIdx.x;
    const int tx = t & 15, ty = t >> 4;
    const int m0 = blockIdx.y * BM, n0 = blockIdx.x * BN;

    const int ar = t >> 1, ac = (t & 1) * 8;      // A tile: 128 rows x 16 cols
    const int wr = t >> 4, wc = (t & 15) * 8;     // W tile: 16 rows x 128 cols

    float acc[8][8];
    #pragma unroll
    for (int i = 0; i < 8; i++) {
        #pragma unroll
        for (int j = 0; j < 8; j++) acc[i][j] = 0.f;
    }

    for (int k0 = 0; k0 < K; k0 += BK) {
        const float4 a0 = *(const float4*)&A[(size_t)(m0 + ar) * lda + k0 + ac];
        const float4 a1 = *(const float4*)&A[(size_t)(m0 + ar) * lda + k0 + ac + 4];
        const float4 w0 = *(const float4*)&W[(size_t)(k0 + wr) * ldw + n0 + wc];
        const float4 w1 = *(const float4*)&W[(size_t)(k0 + wr) * ldw + n0 + wc + 4];
        __syncthreads();   // previous iteration's compute done
        As[ac+0][ar] = a0.x; As[ac+1][ar] = a0.y; As[ac+2][ar] = a0.z; As[ac+3][ar] = a0.w;
        As[ac+4][ar] = a1.x; As[ac+5][ar] = a1.y; As[ac+6][ar] = a1.z; As[ac+7][ar] = a1.w;
        *(float4*)&Ws[wr][wc]     = w0;
        *(float4*)&Ws[wr][wc + 4] = w1;
        __syncthreads();   // tiles visible
        #pragma unroll
        for (int k = 0; k < BK; k++) {
            const float4 aA = *(const float4*)&As[k][ty*4];
            const float4 aB = *(const float4*)&As[k][ty*4 + 64];
            const float4 bA = *(const float4*)&Ws[k][tx*4];
            const float4 bB = *(const float4*)&Ws[k][tx*4 + 64];
            const float av[8] = {aA.x,aA.y,aA.z,aA.w,aB.x,aB.y,aB.z,aB.w};
            const float bv[8] = {bA.x,bA.y,bA.z,bA.w,bB.x,bB.y,bB.z,bB.w};
            #pragma unroll
            for (int i = 0; i < 8; i++) {
                #pragma unroll
                for (int j = 0; j < 8; j++) acc[i][j] += av[i] * bv[j];
            }
        }
    }

    #pragma unroll
    for (int i = 0; i < 8; i++) {
        const int row = m0 + ty*4 + (i & 3) + (i >> 2) * 64;
        #pragma unroll
        for (int jh = 0; jh < 2; jh++) {
            const int col = n0 + tx*4 + jh * 64;
            float4 v;
            v.x = acc[i][jh*4+0];
            v.y = acc[i][jh*4+1];
            v.z = acc[i][jh*4+2];
            v.w = acc[i][jh*4+3];
            if (EPI != 3) {
                const float4 bb = *(const float4*)&bias[col];
                v.x += bb.x; v.y += bb.y; v.z += bb.z; v.w += bb.w;
            }
            if (EPI == 1) {
                v.x = fmaxf(v.x, 0.f); v.y = fmaxf(v.y, 0.f);
                v.z = fmaxf(v.z, 0.f); v.w = fmaxf(v.w, 0.f);
            }
            if (EPI == 2) {
                const float4 rr = *(const float4*)&resid[(size_t)row * ldc + col];
                v.x += rr.x; v.y += rr.y; v.z += rr.z; v.w += rr.w;
            }
            if (EPI == 3) {
                const float4 cc = *(const float4*)&C[(size_t)row * ldc + col];
                v.x += cc.x; v.y += cc.y; v.z += cc.z; v.w += cc.w;
            }
            *(float4*)&C[(size_t)row * ldc + col] = v;
        }
    }
}

// ---------------------------------------------------------------------------
// Flash attention, fp32. Row stride `ld` (NQKV for packed heads, HDIM for
// single-head buffers); head index = blockIdx.y. O may alias Q (each block
// reads its own Q rows into LDS before writing O over them).
// Thread (q = t>>2, g = t&3):
//   scores for s = g + 4j (j=0..7)  -> lane LDS addrs 1 row apart (2-way, free)
//   output d-chunks g*16 + c*64     -> lane LDS addrs 16 floats apart (2-way, free)
template<bool CAUSAL>
__global__ __launch_bounds__(256, 1)
void attn_f32(const float* __restrict__ Q, const float* __restrict__ K,
              const float* __restrict__ V, float* __restrict__ O, int ld)
{
    constexpr int QT = 64, ST = 32, LDP = HDIM + 4;
    __shared__ float Qs[QT][LDP];
    __shared__ float Ks[ST][LDP];
    __shared__ float Vs[ST][LDP];

    const int t   = threadIdx.x;
    const int qt0 = blockIdx.x * QT;
    const int h   = blockIdx.y;
    const int b   = blockIdx.z;
    const int q   = t >> 2;     // 0..63
    const int g   = t & 3;

    // load Q tile (64 rows x 256), coalesced float4
    const size_t qbase = ((size_t)b * SEQ + qt0) * ld + (size_t)h * HDIM;
    #pragma unroll
    for (int c = 0; c < 16; c++) {
        const int idx = c * 1024 + t * 4;
        const int r = idx >> 8, col = idx & 255;
        *(float4*)&Qs[r][col] = *(const float4*)&Q[qbase + (size_t)r * ld + col];
    }

    float o[64];
    #pragma unroll
    for (int i = 0; i < 64; i++) o[i] = 0.f;
    float m_run = -INFINITY, l_run = 0.f;

    const int send = CAUSAL ? (qt0 + QT) : SEQ;
    const size_t kbase = (size_t)b * SEQ * ld + (size_t)h * HDIM;
    const int lq = (q & 15) << 2;   // base lane of this q-row inside the wave

    for (int s0 = 0; s0 < send; s0 += ST) {
        __syncthreads();   // prev PV done before overwriting K/V (also covers Q vis)
        #pragma unroll
        for (int c = 0; c < 8; c++) {
            const int idx = c * 1024 + t * 4;
            const int r = idx >> 8, col = idx & 255;
            const size_t goff = kbase + (size_t)(s0 + r) * ld + col;
            *(float4*)&Ks[r][col] = *(const float4*)&K[goff];
            *(float4*)&Vs[r][col] = *(const float4*)&V[goff];
        }
        __syncthreads();

        // ---- scores: 8 dots of length 256 (s = g + 4j) ----
        float p[8];
        #pragma unroll
        for (int j = 0; j < 8; j++) p[j] = 0.f;
        #pragma unroll 4
        for (int kk = 0; kk < HDIM/4; kk++) {
            const float4 qv = *(const float4*)&Qs[q][kk*4];
            #pragma unroll
            for (int j = 0; j < 8; j++) {
                const float4 kv = *(const float4*)&Ks[g + 4*j][kk*4];
                p[j] += qv.x*kv.x + qv.y*kv.y + qv.z*kv.z + qv.w*kv.w;
            }
        }
        float mx = -INFINITY;
        #pragma unroll
        for (int j = 0; j < 8; j++) {
            p[j] *= ATT_SCALE;
            if (CAUSAL && (s0 + g + 4*j > qt0 + q)) p[j] = -1e9f;
            mx = fmaxf(mx, p[j]);
        }
        mx = fmaxf(mx, __shfl_xor(mx, 1));
        mx = fmaxf(mx, __shfl_xor(mx, 2));
        const float newm = fmaxf(m_run, mx);
        float e[8]; float esum = 0.f;
        #pragma unroll
        for (int j = 0; j < 8; j++) { e[j] = __expf(p[j] - newm); esum += e[j]; }
        esum += __shfl_xor(esum, 1);
        esum += __shfl_xor(esum, 2);
        const float corr = __expf(m_run - newm);
        l_run = l_run * corr + esum;
        m_run = newm;
        #pragma unroll
        for (int i = 0; i < 64; i++) o[i] *= corr;

        // ---- PV: s owner lane = lq | (s&3), value e[s>>2] ----
        #pragma unroll
        for (int s = 0; s < ST; s++) {
            const float pv = __shfl(e[s >> 2], lq + (s & 3));
            #pragma unroll
            for (int c = 0; c < 4; c++) {
                #pragma unroll
                for (int i = 0; i < 4; i++) {
                    const float4 vv = *(const float4*)&Vs[s][g*16 + c*64 + i*4];
                    o[c*16 + i*4 + 0] += pv * vv.x;
                    o[c*16 + i*4 + 1] += pv * vv.y;
                    o[c*16 + i*4 + 2] += pv * vv.z;
                    o[c*16 + i*4 + 3] += pv * vv.w;
                }
            }
        }
    }

    const float inv = 1.f / l_run;
    const size_t obase = ((size_t)b * SEQ + qt0 + q) * ld + (size_t)h * HDIM;
    #pragma unroll
    for (int c = 0; c < 4; c++) {
        #pragma unroll
        for (int i = 0; i < 4; i++) {
            float4 v;
            v.x = o[c*16 + i*4 + 0] * inv;
            v.y = o[c*16 + i*4 + 1] * inv;
            v.z = o[c*16 + i*4 + 2] * inv;
            v.w = o[c*16 + i*4 + 3] * inv;
            *(float4*)&O[obase + g*16 + c*64 + i*4] = v;
        }
    }
}

// ---------------------------------------------------------------------------
// LayerNorm over last dim (256). One wave per row, 4 rows per block. In-place ok.
__global__ __launch_bounds__(256)
void ln_f32(const float* __restrict__ X, const float* __restrict__ gamma,
            const float* __restrict__ beta, float* __restrict__ Y)
{
    const int lane = threadIdx.x & 63;
    const int row  = blockIdx.x * 4 + (threadIdx.x >> 6);
    const float4 v = *(const float4*)&X[(size_t)row * DMODEL + lane * 4];
    float s = v.x + v.y + v.z + v.w;
    #pragma unroll
    for (int o = 1; o < 64; o <<= 1) s += __shfl_xor(s, o);
    const float mu = s * (1.f / 256.f);
    const float dx = v.x - mu, dy = v.y - mu, dz = v.z - mu, dw = v.w - mu;
    float ss = dx*dx + dy*dy + dz*dz + dw*dw;
    #pragma unroll
    for (int o = 1; o < 64; o <<= 1) ss += __shfl_xor(ss, o);
    const float rstd = rsqrtf(ss * (1.f / 256.f) + LN_EPS);
    const float4 gv = *(const float4*)&gamma[lane * 4];
    const float4 bv = *(const float4*)&beta[lane * 4];
    float4 out;
    out.x = dx * rstd * gv.x + bv.x;
    out.y = dy * rstd * gv.y + bv.y;
    out.z = dz * rstd * gv.z + bv.z;
    out.w = dw * rstd * gv.w + bv.w;
    *(float4*)&Y[(size_t)row * DMODEL + lane * 4] = out;
}

// ---------------------------------------------------------------------------
extern "C" void kernel_launch(void* const* d_in, const int* in_sizes, int n_in,
                              void* d_out, int out_size, void* d_ws, size_t ws_size,
                              hipStream_t stream)
{
    const float* x    = (const float*)d_in[0];
    const float* ctx  = (const float*)d_in[1];
    const float* Wq1  = (const float*)d_in[2];
    const float* bq1  = (const float*)d_in[3];
    const float* Wk1  = (const float*)d_in[4];
    const float* bk1  = (const float*)d_in[5];
    const float* Wv1  = (const float*)d_in[6];
    const float* bv1  = (const float*)d_in[7];
    const float* Wo1  = (const float*)d_in[8];
    const float* bo1  = (const float*)d_in[9];
    const float* g1   = (const float*)d_in[10];
    const float* be1  = (const float*)d_in[11];
    const float* Wq2  = (const float*)d_in[12];
    const float* bq2  = (const float*)d_in[13];
    const float* Wk2  = (const float*)d_in[14];
    const float* bk2  = (const float*)d_in[15];
    const float* Wv2  = (const float*)d_in[16];
    const float* bv2  = (const float*)d_in[17];
    const float* Wo2  = (const float*)d_in[18];
    const float* bo2  = (const float*)d_in[19];
    const float* g2   = (const float*)d_in[20];
    const float* be2  = (const float*)d_in[21];
    const float* W1   = (const float*)d_in[22];
    const float* b1   = (const float*)d_in[23];
    const float* W2   = (const float*)d_in[24];
    const float* b2   = (const float*)d_in[25];
    const float* g3   = (const float*)d_in[26];
    const float* be3  = (const float*)d_in[27];
    (void)in_sizes; (void)n_in; (void)out_size;

    float* ws = (float*)d_ws;
    float* out = (float*)d_out;
    const size_t SZ_QKV  = (size_t)MROWS * NQKV;   // 16M floats (64 MiB)
    const size_t SZ_X    = (size_t)MROWS * DMODEL; // 2M floats (8 MiB)
    const size_t SZ_HEAD = (size_t)MROWS * HDIM;   // 2M floats (8 MiB)
    const size_t PLANA_BYTES = (3*SZ_QKV + 3*SZ_X) * sizeof(float);   // 216 MiB

    const dim3 blk(256);
    const dim3 gLN(MROWS/4);

    if (ws_size >= PLANA_BYTES) {
        // ===== Plan A: full-width QKV buffers, attention O in-place over Q =====
        float* bufQ  = ws;                  // 64 MiB (O aliases it)
        float* bufK  = ws + SZ_QKV;         // 64 MiB (FFN hidden overlaps later)
        float* bufV  = ws + 2*SZ_QKV;       // 64 MiB
        float* bufY  = ws + 3*SZ_QKV;       // 8 MiB
        float* bufX1 = bufY + SZ_X;         // 8 MiB
        float* bufX2 = bufX1 + SZ_X;        // 8 MiB
        float* bufH  = bufK;                // [8192,1024] = 32 MiB, bufK dead then

        const dim3 gQKV(NQKV/128, MROWS/128);
        const dim3 gOut(DMODEL/128, MROWS/128);
        const dim3 gF1(DFF/128, MROWS/128);
        const dim3 gAttn(SEQ/64, NHEADS, BATCH);

        // causal self-attention + add&norm
        gemm_f32<0><<<gQKV, blk, 0, stream>>>(x, Wq1, bq1, nullptr, bufQ, DMODEL, DMODEL, NQKV, NQKV);
        gemm_f32<0><<<gQKV, blk, 0, stream>>>(x, Wk1, bk1, nullptr, bufK, DMODEL, DMODEL, NQKV, NQKV);
        gemm_f32<0><<<gQKV, blk, 0, stream>>>(x, Wv1, bv1, nullptr, bufV, DMODEL, DMODEL, NQKV, NQKV);
        attn_f32<true><<<gAttn, blk, 0, stream>>>(bufQ, bufK, bufV, bufQ, NQKV);
        gemm_f32<2><<<gOut, blk, 0, stream>>>(bufQ, Wo1, bo1, x, bufY, NQKV, NQKV, DMODEL, DMODEL);
        ln_f32<<<gLN, blk, 0, stream>>>(bufY, g1, be1, bufX1);
        // cross-attention + add&norm
        gemm_f32<0><<<gQKV, blk, 0, stream>>>(bufX1, Wq2, bq2, nullptr, bufQ, DMODEL, DMODEL, NQKV, NQKV);
        gemm_f32<0><<<gQKV, blk, 0, stream>>>(ctx,  Wk2, bk2, nullptr, bufK, DMODEL, DMODEL, NQKV, NQKV);
        gemm_f32<0><<<gQKV, blk, 0, stream>>>(ctx,  Wv2, bv2, nullptr, bufV, DMODEL, DMODEL, NQKV, NQKV);
        attn_f32<false><<<gAttn, blk, 0, stream>>>(bufQ, bufK, bufV, bufQ, NQKV);
        gemm_f32<2><<<gOut, blk, 0, stream>>>(bufQ, Wo2, bo2, bufX1, bufY, NQKV, NQKV, DMODEL, DMODEL);
        ln_f32<<<gLN, blk, 0, stream>>>(bufY, g2, be2, bufX2);
        // FFN + add&norm
        gemm_f32<1><<<gF1,  blk, 0, stream>>>(bufX2, W1, b1, nullptr, bufH, DMODEL, DMODEL, DFF, DFF);
        gemm_f32<2><<<gOut, blk, 0, stream>>>(bufH, W2, b2, bufX2, bufY, DFF, DFF, DMODEL, DMODEL);
        ln_f32<<<gLN, blk, 0, stream>>>(bufY, g3, be3, out);
    } else {
        // ===== Plan B: head-blocked attention, 40 MiB workspace =====
        // layout: X1(8) X2(8) Qh(8) Kh(8) Vh(8); Y lives in d_out; FFN H (16 MiB
        // per half-pass) overlaps Qh+Kh.
        float* bufX1 = ws;
        float* bufX2 = ws + SZ_X;
        float* bufQh = ws + 2*SZ_X;
        float* bufKh = bufQh + SZ_HEAD;
        float* bufVh = bufQh + 2*SZ_HEAD;
        float* bufH  = bufQh;               // [4096,1024] per half-pass
        float* bufY  = out;

        const dim3 gHead(HDIM/128, MROWS/128);           // (2,64)
        const dim3 gAttn1(SEQ/64, 1, BATCH);             // (16,1,8)
        const dim3 gFh1(DFF/128, (MROWS/2)/128);         // (8,32)
        const dim3 gFh2(DMODEL/128, (MROWS/2)/128);      // (2,32)

        for (int pass = 0; pass < 2; pass++) {
            const bool self = (pass == 0);
            const float* qsrc = self ? x : bufX1;
            const float* kvsrc = self ? x : ctx;
            const float* Wq = self ? Wq1 : Wq2;  const float* bq = self ? bq1 : bq2;
            const float* Wk = self ? Wk1 : Wk2;  const float* bk = self ? bk1 : bk2;
            const float* Wv = self ? Wv1 : Wv2;  const float* bv = self ? bv1 : bv2;
            const float* Wo = self ? Wo1 : Wo2;  const float* bo = self ? bo1 : bo2;
            const float* resid = self ? x : bufX1;
            for (int h = 0; h < NHEADS; h++) {
                gemm_f32<0><<<gHead, blk, 0, stream>>>(qsrc,  Wq + h*HDIM, bq + h*HDIM, nullptr, bufQh, DMODEL, DMODEL, NQKV, HDIM);
                gemm_f32<0><<<gHead, blk, 0, stream>>>(kvsrc, Wk + h*HDIM, bk + h*HDIM, nullptr, bufKh, DMODEL, DMODEL, NQKV, HDIM);
                gemm_f32<0><<<gHead, blk, 0, stream>>>(kvsrc, Wv + h*HDIM, bv + h*HDIM, nullptr, bufVh, DMODEL, DMODEL, NQKV, HDIM);
                if (self) attn_f32<true><<<gAttn1, blk, 0, stream>>>(bufQh, bufKh, bufVh, bufQh, HDIM);
                else      attn_f32<false><<<gAttn1, blk, 0, stream>>>(bufQh, bufKh, bufVh, bufQh, HDIM);
                if (h == 0) gemm_f32<2><<<gHead, blk, 0, stream>>>(bufQh, Wo + (size_t)h*HDIM*DMODEL, bo, resid, bufY, HDIM, HDIM, DMODEL, DMODEL);
                else        gemm_f32<3><<<gHead, blk, 0, stream>>>(bufQh, Wo + (size_t)h*HDIM*DMODEL, nullptr, nullptr, bufY, HDIM, HDIM, DMODEL, DMODEL);
            }
            ln_f32<<<gLN, blk, 0, stream>>>(bufY, self ? g1 : g2, self ? be1 : be2, self ? bufX1 : bufX2);
        }
        // FFN + add&norm, two row-halves so H fits in 16 MiB
        for (int half = 0; half < 2; half++) {
            const size_t ro = (size_t)half * (MROWS/2) * DMODEL;
            gemm_f32<1><<<gFh1, blk, 0, stream>>>(bufX2 + ro, W1, b1, nullptr, bufH, DMODEL, DMODEL, DFF, DFF);
            gemm_f32<2><<<gFh2, blk, 0, stream>>>(bufH, W2, b2, bufX2 + ro, bufY + ro, DFF, DFF, DMODEL, DMODEL);
        }
        ln_f32<<<gLN, blk, 0, stream>>>(bufY, g3, be3, out);
    }
}

// Round 3
// 5270.778 us; speedup vs baseline: 1.1995x; 1.1995x over previous
//
#include <hip/hip_runtime.h>
#include <hip/hip_bf16.h>
#include <math.h>

#define BATCH   8
#define SEQ     1024
#define DMODEL  256
#define NHEADS  8
#define HDIM    256
#define NQKV    2048      /* NHEADS*HDIM */
#define DFF     1024
#define MROWS   (BATCH*SEQ)
#define LN_EPS  1e-3f
#define ATT_SCALE 0.0625f /* 1/sqrt(256) */

typedef unsigned int  uint;
typedef unsigned short ushort;
typedef __attribute__((ext_vector_type(8))) __bf16 bf16x8;
typedef __attribute__((ext_vector_type(4))) float   f32x4;
typedef __attribute__((ext_vector_type(4))) ushort  ushort4v;

__device__ __forceinline__ float b2f(ushort h) {
    union { uint u; float f; } v; v.u = ((uint)h) << 16; return v.f;
}
__device__ __forceinline__ ushort f2b(float f) {
    union { float f; uint u; } v; v.f = f;
    return (ushort)((v.u + 0x7FFFu + ((v.u >> 16) & 1u)) >> 16);
}
__device__ __forceinline__ uint pk2(float a, float b) {
    return (uint)f2b(a) | ((uint)f2b(b) << 16);
}

// ---------------------------------------------------------------------------
// bf16 MFMA GEMM: C[M,128-block] = A[M,K](bf16) @ Bt[N,K](bf16)^T + epilogue.
// EPI: 0 = +bias, 1 = +bias+ReLU, 2 = +bias+resid(fp32). OUTBF: 1 = bf16 C.
// 128x128 tile, BK=64, 4 waves each owning a 64x64 quadrant (4x4 of 16x16).
// LDS tiles XOR-swizzled (byte ^ ((row&7)<<4)) on both write and read sides.
template<int EPI, int OUTBF>
__global__ __launch_bounds__(256, 2)
void gemm_bf16(const ushort* __restrict__ A, const ushort* __restrict__ Bt,
               const float* __restrict__ bias, const float* __restrict__ resid,
               void* __restrict__ Cv, int K, int lda, int ldc)
{
    __shared__ ushort As[128 * 64];
    __shared__ ushort Bs[128 * 64];
    const int t  = threadIdx.x;
    const int l  = t & 63;
    const int w  = t >> 6;
    const int wm = w >> 1, wn = w & 1;
    const int m0 = blockIdx.y * 128, n0 = blockIdx.x * 128;
    const int lg = l >> 4, lr = l & 15;

    f32x4 acc[4][4];
    #pragma unroll
    for (int i = 0; i < 4; i++)
        #pragma unroll
        for (int j = 0; j < 4; j++)
            acc[i][j] = (f32x4){0.f, 0.f, 0.f, 0.f};

    for (int k0 = 0; k0 < K; k0 += 64) {
        uint4 av[4], bv[4];
        #pragma unroll
        for (int j = 0; j < 4; j++) {
            const int chunk = t + j * 256;          // 0..1023
            const int row   = chunk >> 3;           // 0..127
            const int ce    = (chunk & 7) * 8;      // element col
            av[j] = *(const uint4*)&A [(size_t)(m0 + row) * lda + k0 + ce];
            bv[j] = *(const uint4*)&Bt[(size_t)(n0 + row) * K   + k0 + ce];
        }
        __syncthreads();   // previous iteration's reads done
        #pragma unroll
        for (int j = 0; j < 4; j++) {
            const int chunk = t + j * 256;
            const int row   = chunk >> 3;
            const int woff  = (chunk * 16) ^ ((row & 7) << 4);
            *(uint4*)((char*)As + woff) = av[j];
            *(uint4*)((char*)Bs + woff) = bv[j];
        }
        __syncthreads();   // tiles visible
        #pragma unroll
        for (int c = 0; c < 2; c++) {
            bf16x8 af[4], bf[4];
            #pragma unroll
            for (int i = 0; i < 4; i++) {
                const int rowA = wm * 64 + i * 16 + lr;
                const int offA = (rowA * 128 + c * 64 + lg * 16) ^ ((rowA & 7) << 4);
                af[i] = *(const bf16x8*)((const char*)As + offA);
                const int rowB = wn * 64 + i * 16 + lr;
                const int offB = (rowB * 128 + c * 64 + lg * 16) ^ ((rowB & 7) << 4);
                bf[i] = *(const bf16x8*)((const char*)Bs + offB);
            }
            #pragma unroll
            for (int mi = 0; mi < 4; mi++)
                #pragma unroll
                for (int ni = 0; ni < 4; ni++)
                    acc[mi][ni] = __builtin_amdgcn_mfma_f32_16x16x32_bf16(
                        af[mi], bf[ni], acc[mi][ni], 0, 0, 0);
        }
    }

    // epilogue: C row = m0 + wm*64 + mi*16 + lg*4 + r ; col = n0 + wn*64 + ni*16 + lr
    #pragma unroll
    for (int ni = 0; ni < 4; ni++) {
        const int col = n0 + wn * 64 + ni * 16 + lr;
        const float bb = bias[col];
        #pragma unroll
        for (int mi = 0; mi < 4; mi++) {
            #pragma unroll
            for (int r = 0; r < 4; r++) {
                const int row = m0 + wm * 64 + mi * 16 + lg * 4 + r;
                float v = acc[mi][ni][r] + bb;
                if (EPI == 1) v = fmaxf(v, 0.f);
                if (EPI == 2) v += resid[(size_t)row * ldc + col];
                if (OUTBF) ((ushort*)Cv)[(size_t)row * ldc + col] = f2b(v);
                else       ((float*) Cv)[(size_t)row * ldc + col] = v;
            }
        }
    }
}

// ---------------------------------------------------------------------------
// Flash attention, fp32 compute, bf16 I/O. Q,K,V,O: [B,S,NHEADS*HDIM] bf16,
// row stride ld. O may alias Q (blocks only touch their own (qt,h,b) slice).
template<bool CAUSAL>
__global__ __launch_bounds__(256, 1)
void attn_f32(const ushort* __restrict__ Q, const ushort* __restrict__ K,
              const ushort* __restrict__ V, ushort* __restrict__ O, int ld)
{
    constexpr int QT = 64, ST = 32, LDP = HDIM + 4;
    __shared__ float Qs[QT][LDP];
    __shared__ float Ks[ST][LDP];
    __shared__ float Vs[ST][LDP];

    const int t   = threadIdx.x;
    const int qt0 = blockIdx.x * QT;
    const int h   = blockIdx.y;
    const int b   = blockIdx.z;
    const int q   = t >> 2;     // 0..63
    const int g   = t & 3;

    // load Q tile (64 rows x 256) bf16 -> fp32 LDS
    const size_t qbase = ((size_t)b * SEQ + qt0) * ld + (size_t)h * HDIM;
    #pragma unroll
    for (int c = 0; c < 8; c++) {
        const int idx = c * 2048 + t * 8;
        const int r = idx >> 8, col = idx & 255;
        const uint4 raw = *(const uint4*)&Q[qbase + (size_t)r * ld + col];
        float4 lo, hi;
        lo.x = b2f((ushort)raw.x); lo.y = b2f((ushort)(raw.x >> 16));
        lo.z = b2f((ushort)raw.y); lo.w = b2f((ushort)(raw.y >> 16));
        hi.x = b2f((ushort)raw.z); hi.y = b2f((ushort)(raw.z >> 16));
        hi.z = b2f((ushort)raw.w); hi.w = b2f((ushort)(raw.w >> 16));
        *(float4*)&Qs[r][col]     = lo;
        *(float4*)&Qs[r][col + 4] = hi;
    }

    float o[64];
    #pragma unroll
    for (int i = 0; i < 64; i++) o[i] = 0.f;
    float m_run = -INFINITY, l_run = 0.f;

    const int send = CAUSAL ? (qt0 + QT) : SEQ;
    const size_t kbase = (size_t)b * SEQ * ld + (size_t)h * HDIM;
    const int lq = (q & 15) << 2;   // base lane of this q-row inside the wave

    for (int s0 = 0; s0 < send; s0 += ST) {
        __syncthreads();   // prev PV done before overwriting K/V
        #pragma unroll
        for (int c = 0; c < 4; c++) {
            const int idx = c * 2048 + t * 8;
            const int r = idx >> 8, col = idx & 255;
            const size_t goff = kbase + (size_t)(s0 + r) * ld + col;
            {
                const uint4 raw = *(const uint4*)&K[goff];
                float4 lo, hi;
                lo.x = b2f((ushort)raw.x); lo.y = b2f((ushort)(raw.x >> 16));
                lo.z = b2f((ushort)raw.y); lo.w = b2f((ushort)(raw.y >> 16));
                hi.x = b2f((ushort)raw.z); hi.y = b2f((ushort)(raw.z >> 16));
                hi.z = b2f((ushort)raw.w); hi.w = b2f((ushort)(raw.w >> 16));
                *(float4*)&Ks[r][col]     = lo;
                *(float4*)&Ks[r][col + 4] = hi;
            }
            {
                const uint4 raw = *(const uint4*)&V[goff];
                float4 lo, hi;
                lo.x = b2f((ushort)raw.x); lo.y = b2f((ushort)(raw.x >> 16));
                lo.z = b2f((ushort)raw.y); lo.w = b2f((ushort)(raw.y >> 16));
                hi.x = b2f((ushort)raw.z); hi.y = b2f((ushort)(raw.z >> 16));
                hi.z = b2f((ushort)raw.w); hi.w = b2f((ushort)(raw.w >> 16));
                *(float4*)&Vs[r][col]     = lo;
                *(float4*)&Vs[r][col + 4] = hi;
            }
        }
        __syncthreads();

        // ---- scores: 8 dots of length 256 (s = g + 4j) ----
        float p[8];
        #pragma unroll
        for (int j = 0; j < 8; j++) p[j] = 0.f;
        #pragma unroll 4
        for (int kk = 0; kk < HDIM/4; kk++) {
            const float4 qv = *(const float4*)&Qs[q][kk*4];
            #pragma unroll
            for (int j = 0; j < 8; j++) {
                const float4 kv = *(const float4*)&Ks[g + 4*j][kk*4];
                p[j] += qv.x*kv.x + qv.y*kv.y + qv.z*kv.z + qv.w*kv.w;
            }
        }
        float mx = -INFINITY;
        #pragma unroll
        for (int j = 0; j < 8; j++) {
            p[j] *= ATT_SCALE;
            if (CAUSAL && (s0 + g + 4*j > qt0 + q)) p[j] = -1e9f;
            mx = fmaxf(mx, p[j]);
        }
        mx = fmaxf(mx, __shfl_xor(mx, 1));
        mx = fmaxf(mx, __shfl_xor(mx, 2));
        const float newm = fmaxf(m_run, mx);
        float e[8]; float esum = 0.f;
        #pragma unroll
        for (int j = 0; j < 8; j++) { e[j] = __expf(p[j] - newm); esum += e[j]; }
        esum += __shfl_xor(esum, 1);
        esum += __shfl_xor(esum, 2);
        const float corr = __expf(m_run - newm);
        l_run = l_run * corr + esum;
        m_run = newm;
        #pragma unroll
        for (int i = 0; i < 64; i++) o[i] *= corr;

        // ---- PV: s owner lane = lq | (s&3), value e[s>>2] ----
        #pragma unroll
        for (int s = 0; s < ST; s++) {
            const float pv = __shfl(e[s >> 2], lq + (s & 3));
            #pragma unroll
            for (int c = 0; c < 4; c++) {
                #pragma unroll
                for (int i = 0; i < 4; i++) {
                    const float4 vv = *(const float4*)&Vs[s][g*16 + c*64 + i*4];
                    o[c*16 + i*4 + 0] += pv * vv.x;
                    o[c*16 + i*4 + 1] += pv * vv.y;
                    o[c*16 + i*4 + 2] += pv * vv.z;
                    o[c*16 + i*4 + 3] += pv * vv.w;
                }
            }
        }
    }

    const float inv = 1.f / l_run;
    const size_t obase = ((size_t)b * SEQ + qt0 + q) * ld + (size_t)h * HDIM;
    #pragma unroll
    for (int c = 0; c < 4; c++) {
        uint4 p0;
        p0.x = pk2(o[c*16 + 0] * inv, o[c*16 + 1] * inv);
        p0.y = pk2(o[c*16 + 2] * inv, o[c*16 + 3] * inv);
        p0.z = pk2(o[c*16 + 4] * inv, o[c*16 + 5] * inv);
        p0.w = pk2(o[c*16 + 6] * inv, o[c*16 + 7] * inv);
        uint4 p1;
        p1.x = pk2(o[c*16 + 8] * inv, o[c*16 + 9] * inv);
        p1.y = pk2(o[c*16 +10] * inv, o[c*16 +11] * inv);
        p1.z = pk2(o[c*16 +12] * inv, o[c*16 +13] * inv);
        p1.w = pk2(o[c*16 +14] * inv, o[c*16 +15] * inv);
        *(uint4*)&O[obase + g*16 + c*64]     = p0;
        *(uint4*)&O[obase + g*16 + c*64 + 8] = p1;
    }
}

// ---------------------------------------------------------------------------
// LayerNorm over last dim (256). One wave per row, 4 rows per block.
// Optional bf16 dual write (Yb may be null).
__global__ __launch_bounds__(256)
void ln_f32(const float* __restrict__ X, const float* __restrict__ gamma,
            const float* __restrict__ beta, float* __restrict__ Y,
            ushort* __restrict__ Yb)
{
    const int lane = threadIdx.x & 63;
    const int row  = blockIdx.x * 4 + (threadIdx.x >> 6);
    const float4 v = *(const float4*)&X[(size_t)row * DMODEL + lane * 4];
    float s = v.x + v.y + v.z + v.w;
    #pragma unroll
    for (int o = 1; o < 64; o <<= 1) s += __shfl_xor(s, o);
    const float mu = s * (1.f / 256.f);
    const float dx = v.x - mu, dy = v.y - mu, dz = v.z - mu, dw = v.w - mu;
    float ss = dx*dx + dy*dy + dz*dz + dw*dw;
    #pragma unroll
    for (int o = 1; o < 64; o <<= 1) ss += __shfl_xor(ss, o);
    const float rstd = rsqrtf(ss * (1.f / 256.f) + LN_EPS);
    const float4 gv = *(const float4*)&gamma[lane * 4];
    const float4 bv = *(const float4*)&beta[lane * 4];
    float4 out;
    out.x = dx * rstd * gv.x + bv.x;
    out.y = dy * rstd * gv.y + bv.y;
    out.z = dz * rstd * gv.z + bv.z;
    out.w = dw * rstd * gv.w + bv.w;
    *(float4*)&Y[(size_t)row * DMODEL + lane * 4] = out;
    if (Yb) {
        uint2 p; p.x = pk2(out.x, out.y); p.y = pk2(out.z, out.w);
        *(uint2*)&Yb[(size_t)row * DMODEL + lane * 4] = p;
    }
}

// ---------------------------------------------------------------------------
// Elementwise fp32 -> bf16 cast (n8 = elements/8).
__global__ __launch_bounds__(256)
void cast_f2b(const float* __restrict__ X, ushort* __restrict__ Y, int n8)
{
    const int i = blockIdx.x * 256 + threadIdx.x;
    if (i < n8) {
        const float4 a = *(const float4*)&X[(size_t)i * 8];
        const float4 b = *(const float4*)&X[(size_t)i * 8 + 4];
        uint4 o;
        o.x = pk2(a.x, a.y); o.y = pk2(a.z, a.w);
        o.z = pk2(b.x, b.y); o.w = pk2(b.z, b.w);
        *(uint4*)&Y[(size_t)i * 8] = o;
    }
}

// Transpose-cast: W[K][N] fp32 -> Wt[N][K] bf16. Grid (N/32, K/32), block 256.
__global__ __launch_bounds__(256)
void castT_f2b(const float* __restrict__ W, ushort* __restrict__ Wt, int Kd, int Nd)
{
    __shared__ float tile[32][33];
    const int k0 = blockIdx.y * 32, n0 = blockIdx.x * 32;
    const int r  = threadIdx.x >> 3;
    const int c4 = (threadIdx.x & 7) * 4;
    const float4 v = *(const float4*)&W[(size_t)(k0 + r) * Nd + n0 + c4];
    tile[r][c4+0] = v.x; tile[r][c4+1] = v.y; tile[r][c4+2] = v.z; tile[r][c4+3] = v.w;
    __syncthreads();
    ushort4v ov = { f2b(tile[c4+0][r]), f2b(tile[c4+1][r]),
                    f2b(tile[c4+2][r]), f2b(tile[c4+3][r]) };
    *(ushort4v*)&Wt[(size_t)(n0 + r) * Kd + k0 + c4] = ov;
}

// ---------------------------------------------------------------------------
extern "C" void kernel_launch(void* const* d_in, const int* in_sizes, int n_in,
                              void* d_out, int out_size, void* d_ws, size_t ws_size,
                              hipStream_t stream)
{
    const float* x    = (const float*)d_in[0];
    const float* ctx  = (const float*)d_in[1];
    const float* Wq1  = (const float*)d_in[2];
    const float* bq1  = (const float*)d_in[3];
    const float* Wk1  = (const float*)d_in[4];
    const float* bk1  = (const float*)d_in[5];
    const float* Wv1  = (const float*)d_in[6];
    const float* bv1  = (const float*)d_in[7];
    const float* Wo1  = (const float*)d_in[8];
    const float* bo1  = (const float*)d_in[9];
    const float* g1   = (const float*)d_in[10];
    const float* be1  = (const float*)d_in[11];
    const float* Wq2  = (const float*)d_in[12];
    const float* bq2  = (const float*)d_in[13];
    const float* Wk2  = (const float*)d_in[14];
    const float* bk2  = (const float*)d_in[15];
    const float* Wv2  = (const float*)d_in[16];
    const float* bv2  = (const float*)d_in[17];
    const float* Wo2  = (const float*)d_in[18];
    const float* bo2  = (const float*)d_in[19];
    const float* g2   = (const float*)d_in[20];
    const float* be2  = (const float*)d_in[21];
    const float* W1   = (const float*)d_in[22];
    const float* b1   = (const float*)d_in[23];
    const float* W2   = (const float*)d_in[24];
    const float* b2   = (const float*)d_in[25];
    const float* g3   = (const float*)d_in[26];
    const float* be3  = (const float*)d_in[27];
    (void)in_sizes; (void)n_in; (void)out_size; (void)ws_size;

    char* base = (char*)d_ws;
    const size_t MB1 = 1024 * 1024;
    ushort* Qb   = (ushort*)(base + 0 * MB1);     // 32 MiB (O aliases)
    ushort* Kb   = (ushort*)(base + 32 * MB1);    // 32 MiB
    ushort* Vb   = (ushort*)(base + 64 * MB1);    // 32 MiB
    float*  Yf   = (float*) (base + 96 * MB1);    // 8 MiB
    float*  X1f  = (float*) (base + 104 * MB1);   // 8 MiB
    float*  X2f  = (float*) (base + 112 * MB1);   // 8 MiB
    ushort* xb   = (ushort*)(base + 120 * MB1);   // 4 MiB
    ushort* ctxb = (ushort*)(base + 124 * MB1);   // 4 MiB
    ushort* X1b  = (ushort*)(base + 128 * MB1);   // 4 MiB
    ushort* X2b  = (ushort*)(base + 132 * MB1);   // 4 MiB
    ushort* wq1t = (ushort*)(base + 136 * MB1);   // 1 MiB each
    ushort* wk1t = (ushort*)(base + 137 * MB1);
    ushort* wv1t = (ushort*)(base + 138 * MB1);
    ushort* wo1t = (ushort*)(base + 139 * MB1);
    ushort* wq2t = (ushort*)(base + 140 * MB1);
    ushort* wk2t = (ushort*)(base + 141 * MB1);
    ushort* wv2t = (ushort*)(base + 142 * MB1);
    ushort* wo2t = (ushort*)(base + 143 * MB1);
    ushort* w1t  = (ushort*)(base + 144 * MB1);   // 0.5 MiB
    ushort* w2t  = (ushort*)(base + 144 * MB1 + 512 * 1024);
    ushort* Hb   = (ushort*)(base + 145 * MB1);   // 16 MiB -> ends at 161 MiB

    const dim3 blk(256);
    const dim3 gQKV(NQKV/128, MROWS/128);   // (16,64)
    const dim3 gOut(DMODEL/128, MROWS/128); // (2,64)
    const dim3 gF1(DFF/128, MROWS/128);     // (8,64)
    const dim3 gAttn(SEQ/64, NHEADS, BATCH);
    const dim3 gLN(MROWS/4);

    // ---- casts ----
    cast_f2b<<<dim3((MROWS*DMODEL/8 + 255)/256), blk, 0, stream>>>(x,   xb,   MROWS*DMODEL/8);
    cast_f2b<<<dim3((MROWS*DMODEL/8 + 255)/256), blk, 0, stream>>>(ctx, ctxb, MROWS*DMODEL/8);
    castT_f2b<<<dim3(NQKV/32, DMODEL/32), blk, 0, stream>>>(Wq1, wq1t, DMODEL, NQKV);
    castT_f2b<<<dim3(NQKV/32, DMODEL/32), blk, 0, stream>>>(Wk1, wk1t, DMODEL, NQKV);
    castT_f2b<<<dim3(NQKV/32, DMODEL/32), blk, 0, stream>>>(Wv1, wv1t, DMODEL, NQKV);
    castT_f2b<<<dim3(DMODEL/32, NQKV/32), blk, 0, stream>>>(Wo1, wo1t, NQKV, DMODEL);
    castT_f2b<<<dim3(NQKV/32, DMODEL/32), blk, 0, stream>>>(Wq2, wq2t, DMODEL, NQKV);
    castT_f2b<<<dim3(NQKV/32, DMODEL/32), blk, 0, stream>>>(Wk2, wk2t, DMODEL, NQKV);
    castT_f2b<<<dim3(NQKV/32, DMODEL/32), blk, 0, stream>>>(Wv2, wv2t, DMODEL, NQKV);
    castT_f2b<<<dim3(DMODEL/32, NQKV/32), blk, 0, stream>>>(Wo2, wo2t, NQKV, DMODEL);
    castT_f2b<<<dim3(DFF/32, DMODEL/32), blk, 0, stream>>>(W1, w1t, DMODEL, DFF);
    castT_f2b<<<dim3(DMODEL/32, DFF/32), blk, 0, stream>>>(W2, w2t, DFF, DMODEL);

    // ---- causal self-attention + add&norm ----
    gemm_bf16<0,1><<<gQKV, blk, 0, stream>>>(xb, wq1t, bq1, nullptr, Qb, DMODEL, DMODEL, NQKV);
    gemm_bf16<0,1><<<gQKV, blk, 0, stream>>>(xb, wk1t, bk1, nullptr, Kb, DMODEL, DMODEL, NQKV);
    gemm_bf16<0,1><<<gQKV, blk, 0, stream>>>(xb, wv1t, bv1, nullptr, Vb, DMODEL, DMODEL, NQKV);
    attn_f32<true><<<gAttn, blk, 0, stream>>>(Qb, Kb, Vb, Qb, NQKV);
    gemm_bf16<2,0><<<gOut, blk, 0, stream>>>(Qb, wo1t, bo1, x, Yf, NQKV, NQKV, DMODEL);
    ln_f32<<<gLN, blk, 0, stream>>>(Yf, g1, be1, X1f, X1b);
    // ---- cross-attention + add&norm ----
    gemm_bf16<0,1><<<gQKV, blk, 0, stream>>>(X1b,  wq2t, bq2, nullptr, Qb, DMODEL, DMODEL, NQKV);
    gemm_bf16<0,1><<<gQKV, blk, 0, stream>>>(ctxb, wk2t, bk2, nullptr, Kb, DMODEL, DMODEL, NQKV);
    gemm_bf16<0,1><<<gQKV, blk, 0, stream>>>(ctxb, wv2t, bv2, nullptr, Vb, DMODEL, DMODEL, NQKV);
    attn_f32<false><<<gAttn, blk, 0, stream>>>(Qb, Kb, Vb, Qb, NQKV);
    gemm_bf16<2,0><<<gOut, blk, 0, stream>>>(Qb, wo2t, bo2, X1f, Yf, NQKV, NQKV, DMODEL);
    ln_f32<<<gLN, blk, 0, stream>>>(Yf, g2, be2, X2f, X2b);
    // ---- FFN + add&norm ----
    gemm_bf16<1,1><<<gF1,  blk, 0, stream>>>(X2b, w1t, b1, nullptr, Hb, DMODEL, DMODEL, DFF);
    gemm_bf16<2,0><<<gOut, blk, 0, stream>>>(Hb, w2t, b2, X2f, Yf, DFF, DFF, DMODEL);
    ln_f32<<<gLN, blk, 0, stream>>>(Yf, g3, be3, (float*)d_out, nullptr);
}

// Round 4
// 1604.991 us; speedup vs baseline: 3.9393x; 3.2840x over previous
//
#include <hip/hip_runtime.h>
#include <hip/hip_bf16.h>
#include <math.h>

#define BATCH   8
#define SEQ     1024
#define DMODEL  256
#define NHEADS  8
#define HDIM    256
#define NQKV    2048      /* NHEADS*HDIM */
#define DFF     1024
#define MROWS   (BATCH*SEQ)
#define LN_EPS  1e-3f
#define ATT_SCALE 0.0625f /* 1/sqrt(256) */

typedef unsigned int  uint;
typedef unsigned short ushort;
typedef __attribute__((ext_vector_type(8))) __bf16 bf16x8;
typedef __attribute__((ext_vector_type(4))) float   f32x4;
typedef __attribute__((ext_vector_type(4))) ushort  ushort4v;

__device__ __forceinline__ float b2f(ushort h) {
    union { uint u; float f; } v; v.u = ((uint)h) << 16; return v.f;
}
__device__ __forceinline__ ushort f2b(float f) {
    union { float f; uint u; } v; v.f = f;
    return (ushort)((v.u + 0x7FFFu + ((v.u >> 16) & 1u)) >> 16);
}
__device__ __forceinline__ uint pk2(float a, float b) {
    return (uint)f2b(a) | ((uint)f2b(b) << 16);
}

// ---------------------------------------------------------------------------
// bf16 MFMA GEMM: C[M,128-block] = A[M,K](bf16) @ Bt[N,K](bf16)^T + epilogue.
// EPI: 0 = +bias, 1 = +bias+ReLU, 2 = +bias+resid(fp32). OUTBF: 1 = bf16 C.
// 128x128 tile, BK=64, 4 waves each owning a 64x64 quadrant (4x4 of 16x16).
// LDS tiles XOR-swizzled (byte ^ ((row&7)<<4)): slot-uniform b128 access.
template<int EPI, int OUTBF>
__global__ __launch_bounds__(256, 2)
void gemm_bf16(const ushort* __restrict__ A, const ushort* __restrict__ Bt,
               const float* __restrict__ bias, const float* __restrict__ resid,
               void* __restrict__ Cv, int K, int lda, int ldc)
{
    __shared__ ushort As[128 * 64];
    __shared__ ushort Bs[128 * 64];
    const int t  = threadIdx.x;
    const int l  = t & 63;
    const int w  = t >> 6;
    const int wm = w >> 1, wn = w & 1;
    const int m0 = blockIdx.y * 128, n0 = blockIdx.x * 128;
    const int lg = l >> 4, lr = l & 15;

    f32x4 acc[4][4];
    #pragma unroll
    for (int i = 0; i < 4; i++)
        #pragma unroll
        for (int j = 0; j < 4; j++)
            acc[i][j] = (f32x4){0.f, 0.f, 0.f, 0.f};

    for (int k0 = 0; k0 < K; k0 += 64) {
        uint4 av[4], bv[4];
        #pragma unroll
        for (int j = 0; j < 4; j++) {
            const int chunk = t + j * 256;          // 0..1023
            const int row   = chunk >> 3;           // 0..127
            const int ce    = (chunk & 7) * 8;      // element col
            av[j] = *(const uint4*)&A [(size_t)(m0 + row) * lda + k0 + ce];
            bv[j] = *(const uint4*)&Bt[(size_t)(n0 + row) * K   + k0 + ce];
        }
        __syncthreads();   // previous iteration's reads done
        #pragma unroll
        for (int j = 0; j < 4; j++) {
            const int chunk = t + j * 256;
            const int row   = chunk >> 3;
            const int woff  = (chunk * 16) ^ ((row & 7) << 4);
            *(uint4*)((char*)As + woff) = av[j];
            *(uint4*)((char*)Bs + woff) = bv[j];
        }
        __syncthreads();   // tiles visible
        #pragma unroll
        for (int c = 0; c < 2; c++) {
            bf16x8 af[4], bf[4];
            #pragma unroll
            for (int i = 0; i < 4; i++) {
                const int rowA = wm * 64 + i * 16 + lr;
                const int offA = (rowA * 128 + c * 64 + lg * 16) ^ ((rowA & 7) << 4);
                af[i] = *(const bf16x8*)((const char*)As + offA);
                const int rowB = wn * 64 + i * 16 + lr;
                const int offB = (rowB * 128 + c * 64 + lg * 16) ^ ((rowB & 7) << 4);
                bf[i] = *(const bf16x8*)((const char*)Bs + offB);
            }
            #pragma unroll
            for (int mi = 0; mi < 4; mi++)
                #pragma unroll
                for (int ni = 0; ni < 4; ni++)
                    acc[mi][ni] = __builtin_amdgcn_mfma_f32_16x16x32_bf16(
                        af[mi], bf[ni], acc[mi][ni], 0, 0, 0);
        }
    }

    // epilogue: C row = m0 + wm*64 + mi*16 + lg*4 + r ; col = n0 + wn*64 + ni*16 + lr
    #pragma unroll
    for (int ni = 0; ni < 4; ni++) {
        const int col = n0 + wn * 64 + ni * 16 + lr;
        const float bb = bias[col];
        #pragma unroll
        for (int mi = 0; mi < 4; mi++) {
            #pragma unroll
            for (int r = 0; r < 4; r++) {
                const int row = m0 + wm * 64 + mi * 16 + lg * 4 + r;
                float v = acc[mi][ni][r] + bb;
                if (EPI == 1) v = fmaxf(v, 0.f);
                if (EPI == 2) v += resid[(size_t)row * ldc + col];
                if (OUTBF) ((ushort*)Cv)[(size_t)row * ldc + col] = f2b(v);
                else       ((float*) Cv)[(size_t)row * ldc + col] = v;
            }
        }
    }
}

// ---------------------------------------------------------------------------
// V transpose: V[b,s, h*256+d] (bf16) -> Vt[(b*8+h)*256 + d][s] (bf16).
// 64x64 tiles through LDS; coalesced on both sides.
__global__ __launch_bounds__(256)
void vtrans(const ushort* __restrict__ V, ushort* __restrict__ Vt)
{
    __shared__ ushort tl[64][72];
    const int s0 = blockIdx.x * 64;
    const int d0 = blockIdx.y * 64;
    const int bh = blockIdx.z;
    const int b  = bh >> 3, h = bh & 7;
    const int t  = threadIdx.x;
    #pragma unroll
    for (int j = 0; j < 2; j++) {
        const int chunk = t + j * 256;
        const int row = chunk >> 3, c8 = (chunk & 7) * 8;
        *(uint4*)&tl[row][c8] =
            *(const uint4*)&V[((size_t)(b * SEQ + s0 + row)) * NQKV + h * HDIM + d0 + c8];
    }
    __syncthreads();
    #pragma unroll
    for (int j = 0; j < 2; j++) {
        const int chunk = t + j * 256;
        const int dr = chunk >> 3, s8 = (chunk & 7) * 8;
        ushort tmp[8] __attribute__((aligned(16)));
        #pragma unroll
        for (int i = 0; i < 8; i++) tmp[i] = tl[s8 + i][dr];
        *(uint4*)&Vt[((size_t)(bh * HDIM + d0 + dr)) * SEQ + s0 + s8] = *(const uint4*)tmp;
    }
}

// ---------------------------------------------------------------------------
// MFMA flash attention, bf16 in/out, fp32 softmax state.
// Q,K,O: [B,S,NHEADS*HDIM] bf16. Vt: [(b*8+h)*256 + d][s] bf16.
// Block = (b,h) x 64 q-rows; 4 waves, each owns 16 q-rows.
// Wave q-rows as MFMA A rows (lane&15); K tile as B-frags (col=s); S lands in
// C-layout (row=q=lg*4+reg, col=s=st*16+lr). Online softmax per reg, 16-lane
// shfl reduce. P -> per-wave LDS tile -> A-frags for PV against Vt B-frags.
template<bool CAUSAL>
__global__ __launch_bounds__(256, 2)
void attn_mfma(const ushort* __restrict__ Q, const ushort* __restrict__ K,
               const ushort* __restrict__ Vt, ushort* __restrict__ O)
{
    __shared__ __align__(16) char lds[37888];
    // [0,16384):      K tile  [32 s][512B] xor-swizzled ((row&7)<<4)
    // [16384,32768):  Vt tile [256 d][64B] xor-swizzled ((row&3)<<4)
    // [32768,37888):  P per wave: [16 q][80B] (stride 40 ushorts)
    // Q staged once into [0,32768) before the main loop.

    const int t  = threadIdx.x;
    const int w  = t >> 6, l = t & 63;
    const int lg = l >> 4, lr = l & 15;
    const int qt0 = blockIdx.x * 64;
    const int h = blockIdx.y, b = blockIdx.z;

    // ---- stage Q (64 rows x 512B) and pull A-frags into registers ----
    const size_t qgbase = ((size_t)(b * SEQ + qt0)) * NQKV + (size_t)h * HDIM;
    #pragma unroll
    for (int j = 0; j < 8; j++) {
        const int chunk = t + j * 256;
        const int row = chunk >> 5, slot = chunk & 31;
        const uint4 v = *(const uint4*)&Q[qgbase + (size_t)row * NQKV + slot * 8];
        *(uint4*)(lds + row * 512 + ((slot * 16) ^ ((row & 7) << 4))) = v;
    }
    __syncthreads();
    bf16x8 qa[8];
    {
        const int qrow = w * 16 + lr;
        const int sw = (qrow & 7) << 4;
        #pragma unroll
        for (int ks = 0; ks < 8; ks++)
            qa[ks] = *(const bf16x8*)(lds + qrow * 512 + ((lg * 16 + ks * 64) ^ sw));
    }
    __syncthreads();   // before K staging overwrites the region

    f32x4 oacc[16];
    #pragma unroll
    for (int i = 0; i < 16; i++) oacc[i] = (f32x4){0.f, 0.f, 0.f, 0.f};
    float m_[4], l_[4];
    #pragma unroll
    for (int r = 0; r < 4; r++) { m_[r] = -INFINITY; l_[r] = 0.f; }

    ushort* Pw = (ushort*)(lds + 32768 + w * 1280);
    const size_t kgbase = (size_t)b * SEQ * NQKV + (size_t)h * HDIM;
    const size_t vgbase = ((size_t)(b * NHEADS + h)) * HDIM * SEQ;

    const int ntiles = CAUSAL ? (qt0 / 32 + 2) : (SEQ / 32);
    for (int tile = 0; tile < ntiles; tile++) {
        const int s0 = tile * 32;
        // ---- stage K (32x512B) + Vt (256x64B), reg-staged, swizzled ----
        uint4 kv[4], vv[4];
        #pragma unroll
        for (int j = 0; j < 4; j++) {
            const int chunk = t + j * 256;
            const int krow = chunk >> 5, kslot = chunk & 31;
            kv[j] = *(const uint4*)&K[kgbase + (size_t)(s0 + krow) * NQKV + kslot * 8];
            const int vrow = chunk >> 2, vslot = chunk & 3;
            vv[j] = *(const uint4*)&Vt[vgbase + (size_t)vrow * SEQ + s0 + vslot * 8];
        }
        __syncthreads();   // previous tile's LDS reads done
        #pragma unroll
        for (int j = 0; j < 4; j++) {
            const int chunk = t + j * 256;
            const int krow = chunk >> 5, kslot = chunk & 31;
            *(uint4*)(lds + krow * 512 + ((kslot * 16) ^ ((krow & 7) << 4))) = kv[j];
            const int vrow = chunk >> 2, vslot = chunk & 3;
            *(uint4*)(lds + 16384 + vrow * 64 + ((vslot * 16) ^ ((vrow & 3) << 4))) = vv[j];
        }
        __syncthreads();

        // ---- S = Q K^T (2 s-tiles x 8 k-steps) ----
        f32x4 sacc[2];
        sacc[0] = (f32x4){0.f, 0.f, 0.f, 0.f};
        sacc[1] = (f32x4){0.f, 0.f, 0.f, 0.f};
        #pragma unroll
        for (int ks = 0; ks < 8; ks++) {
            #pragma unroll
            for (int st = 0; st < 2; st++) {
                const int srow = st * 16 + lr;
                const bf16x8 kb = *(const bf16x8*)(lds + srow * 512 +
                                   ((lg * 16 + ks * 64) ^ ((srow & 7) << 4)));
                sacc[st] = __builtin_amdgcn_mfma_f32_16x16x32_bf16(qa[ks], kb, sacc[st], 0, 0, 0);
            }
        }

        // ---- online softmax (rows q_w = lg*4+r, 16-lane groups) ----
        const bool maskq = CAUSAL && (s0 + 31 > qt0 + w * 16);
        float e0[4], e1[4], corr[4];
        #pragma unroll
        for (int r = 0; r < 4; r++) {
            float p0 = sacc[0][r] * ATT_SCALE;
            float p1 = sacc[1][r] * ATT_SCALE;
            if (maskq) {
                const int qg = qt0 + w * 16 + lg * 4 + r;
                if (s0 + lr > qg)      p0 = -1e9f;
                if (s0 + 16 + lr > qg) p1 = -1e9f;
            }
            float mx = fmaxf(p0, p1);
            mx = fmaxf(mx, __shfl_xor(mx, 1));
            mx = fmaxf(mx, __shfl_xor(mx, 2));
            mx = fmaxf(mx, __shfl_xor(mx, 4));
            mx = fmaxf(mx, __shfl_xor(mx, 8));
            const float newm = fmaxf(m_[r], mx);
            corr[r] = __expf(m_[r] - newm);
            m_[r] = newm;
            e0[r] = __expf(p0 - newm);
            e1[r] = __expf(p1 - newm);
            float es = e0[r] + e1[r];
            es += __shfl_xor(es, 1);
            es += __shfl_xor(es, 2);
            es += __shfl_xor(es, 4);
            es += __shfl_xor(es, 8);
            l_[r] = l_[r] * corr[r] + es;
        }
        // write P (bf16) to per-wave LDS, rescale O accumulator
        #pragma unroll
        for (int r = 0; r < 4; r++) {
            Pw[(lg * 4 + r) * 40 + lr]      = f2b(e0[r]);
            Pw[(lg * 4 + r) * 40 + 16 + lr] = f2b(e1[r]);
        }
        #pragma unroll
        for (int dt = 0; dt < 16; dt++) {
            oacc[dt][0] *= corr[0]; oacc[dt][1] *= corr[1];
            oacc[dt][2] *= corr[2]; oacc[dt][3] *= corr[3];
        }

        // ---- O += P V (A-frag from P LDS, B-frags from Vt LDS) ----
        const bf16x8 pa = *(const bf16x8*)((const char*)Pw + lr * 80 + lg * 16);
        #pragma unroll
        for (int dt = 0; dt < 16; dt++) {
            const int vrow = dt * 16 + lr;
            const bf16x8 vb = *(const bf16x8*)(lds + 16384 + vrow * 64 +
                               ((lg * 16) ^ ((vrow & 3) << 4)));
            oacc[dt] = __builtin_amdgcn_mfma_f32_16x16x32_bf16(pa, vb, oacc[dt], 0, 0, 0);
        }
    }

    // ---- epilogue: O[q][d] = oacc / l ----
    float inv[4];
    #pragma unroll
    for (int r = 0; r < 4; r++) inv[r] = 1.f / l_[r];
    const size_t obase = ((size_t)(b * SEQ + qt0 + w * 16)) * NQKV + (size_t)h * HDIM;
    #pragma unroll
    for (int dt = 0; dt < 16; dt++) {
        #pragma unroll
        for (int r = 0; r < 4; r++) {
            O[obase + (size_t)(lg * 4 + r) * NQKV + dt * 16 + lr] =
                f2b(oacc[dt][r] * inv[r]);
        }
    }
}

// ---------------------------------------------------------------------------
// LayerNorm over last dim (256). One wave per row, 4 rows per block.
// Optional bf16 dual write (Yb may be null).
__global__ __launch_bounds__(256)
void ln_f32(const float* __restrict__ X, const float* __restrict__ gamma,
            const float* __restrict__ beta, float* __restrict__ Y,
            ushort* __restrict__ Yb)
{
    const int lane = threadIdx.x & 63;
    const int row  = blockIdx.x * 4 + (threadIdx.x >> 6);
    const float4 v = *(const float4*)&X[(size_t)row * DMODEL + lane * 4];
    float s = v.x + v.y + v.z + v.w;
    #pragma unroll
    for (int o = 1; o < 64; o <<= 1) s += __shfl_xor(s, o);
    const float mu = s * (1.f / 256.f);
    const float dx = v.x - mu, dy = v.y - mu, dz = v.z - mu, dw = v.w - mu;
    float ss = dx*dx + dy*dy + dz*dz + dw*dw;
    #pragma unroll
    for (int o = 1; o < 64; o <<= 1) ss += __shfl_xor(ss, o);
    const float rstd = rsqrtf(ss * (1.f / 256.f) + LN_EPS);
    const float4 gv = *(const float4*)&gamma[lane * 4];
    const float4 bv = *(const float4*)&beta[lane * 4];
    float4 out;
    out.x = dx * rstd * gv.x + bv.x;
    out.y = dy * rstd * gv.y + bv.y;
    out.z = dz * rstd * gv.z + bv.z;
    out.w = dw * rstd * gv.w + bv.w;
    *(float4*)&Y[(size_t)row * DMODEL + lane * 4] = out;
    if (Yb) {
        uint2 p; p.x = pk2(out.x, out.y); p.y = pk2(out.z, out.w);
        *(uint2*)&Yb[(size_t)row * DMODEL + lane * 4] = p;
    }
}

// ---------------------------------------------------------------------------
// Elementwise fp32 -> bf16 cast (n8 = elements/8).
__global__ __launch_bounds__(256)
void cast_f2b(const float* __restrict__ X, ushort* __restrict__ Y, int n8)
{
    const int i = blockIdx.x * 256 + threadIdx.x;
    if (i < n8) {
        const float4 a = *(const float4*)&X[(size_t)i * 8];
        const float4 b = *(const float4*)&X[(size_t)i * 8 + 4];
        uint4 o;
        o.x = pk2(a.x, a.y); o.y = pk2(a.z, a.w);
        o.z = pk2(b.x, b.y); o.w = pk2(b.z, b.w);
        *(uint4*)&Y[(size_t)i * 8] = o;
    }
}

// Transpose-cast: W[K][N] fp32 -> Wt[N][K] bf16. Grid (N/32, K/32), block 256.
__global__ __launch_bounds__(256)
void castT_f2b(const float* __restrict__ W, ushort* __restrict__ Wt, int Kd, int Nd)
{
    __shared__ float tile[32][33];
    const int k0 = blockIdx.y * 32, n0 = blockIdx.x * 32;
    const int r  = threadIdx.x >> 3;
    const int c4 = (threadIdx.x & 7) * 4;
    const float4 v = *(const float4*)&W[(size_t)(k0 + r) * Nd + n0 + c4];
    tile[r][c4+0] = v.x; tile[r][c4+1] = v.y; tile[r][c4+2] = v.z; tile[r][c4+3] = v.w;
    __syncthreads();
    ushort4v ov = { f2b(tile[c4+0][r]), f2b(tile[c4+1][r]),
                    f2b(tile[c4+2][r]), f2b(tile[c4+3][r]) };
    *(ushort4v*)&Wt[(size_t)(n0 + r) * Kd + k0 + c4] = ov;
}

// ---------------------------------------------------------------------------
extern "C" void kernel_launch(void* const* d_in, const int* in_sizes, int n_in,
                              void* d_out, int out_size, void* d_ws, size_t ws_size,
                              hipStream_t stream)
{
    const float* x    = (const float*)d_in[0];
    const float* ctx  = (const float*)d_in[1];
    const float* Wq1  = (const float*)d_in[2];
    const float* bq1  = (const float*)d_in[3];
    const float* Wk1  = (const float*)d_in[4];
    const float* bk1  = (const float*)d_in[5];
    const float* Wv1  = (const float*)d_in[6];
    const float* bv1  = (const float*)d_in[7];
    const float* Wo1  = (const float*)d_in[8];
    const float* bo1  = (const float*)d_in[9];
    const float* g1   = (const float*)d_in[10];
    const float* be1  = (const float*)d_in[11];
    const float* Wq2  = (const float*)d_in[12];
    const float* bq2  = (const float*)d_in[13];
    const float* Wk2  = (const float*)d_in[14];
    const float* bk2  = (const float*)d_in[15];
    const float* Wv2  = (const float*)d_in[16];
    const float* bv2  = (const float*)d_in[17];
    const float* Wo2  = (const float*)d_in[18];
    const float* bo2  = (const float*)d_in[19];
    const float* g2   = (const float*)d_in[20];
    const float* be2  = (const float*)d_in[21];
    const float* W1   = (const float*)d_in[22];
    const float* b1   = (const float*)d_in[23];
    const float* W2   = (const float*)d_in[24];
    const float* b2   = (const float*)d_in[25];
    const float* g3   = (const float*)d_in[26];
    const float* be3  = (const float*)d_in[27];
    (void)in_sizes; (void)n_in; (void)out_size; (void)ws_size;

    char* base = (char*)d_ws;
    const size_t MB1 = 1024 * 1024;
    ushort* Qb   = (ushort*)(base + 0 * MB1);     // 32 MiB (O aliases)
    ushort* Kb   = (ushort*)(base + 32 * MB1);    // 32 MiB
    ushort* Vb   = (ushort*)(base + 64 * MB1);    // 32 MiB
    float*  Yf   = (float*) (base + 96 * MB1);    // 8 MiB
    float*  X1f  = (float*) (base + 104 * MB1);   // 8 MiB
    float*  X2f  = (float*) (base + 112 * MB1);   // 8 MiB
    ushort* xb   = (ushort*)(base + 120 * MB1);   // 4 MiB
    ushort* ctxb = (ushort*)(base + 124 * MB1);   // 4 MiB
    ushort* X1b  = (ushort*)(base + 128 * MB1);   // 4 MiB
    ushort* X2b  = (ushort*)(base + 132 * MB1);   // 4 MiB
    ushort* wq1t = (ushort*)(base + 136 * MB1);   // 1 MiB each
    ushort* wk1t = (ushort*)(base + 137 * MB1);
    ushort* wv1t = (ushort*)(base + 138 * MB1);
    ushort* wo1t = (ushort*)(base + 139 * MB1);
    ushort* wq2t = (ushort*)(base + 140 * MB1);
    ushort* wk2t = (ushort*)(base + 141 * MB1);
    ushort* wv2t = (ushort*)(base + 142 * MB1);
    ushort* wo2t = (ushort*)(base + 143 * MB1);
    ushort* w1t  = (ushort*)(base + 144 * MB1);   // 0.5 MiB
    ushort* w2t  = (ushort*)(base + 144 * MB1 + 512 * 1024);
    ushort* Hb   = (ushort*)(base + 145 * MB1);   // 16 MiB (ends 161)
    ushort* Vtg  = (ushort*)(base + 161 * MB1);   // 32 MiB (ends 193)

    const dim3 blk(256);
    const dim3 gQKV(NQKV/128, MROWS/128);   // (16,64)
    const dim3 gOut(DMODEL/128, MROWS/128); // (2,64)
    const dim3 gF1(DFF/128, MROWS/128);     // (8,64)
    const dim3 gAttn(SEQ/64, NHEADS, BATCH);
    const dim3 gVT(SEQ/64, HDIM/64, BATCH*NHEADS);
    const dim3 gLN(MROWS/4);

    // ---- casts ----
    cast_f2b<<<dim3((MROWS*DMODEL/8 + 255)/256), blk, 0, stream>>>(x,   xb,   MROWS*DMODEL/8);
    cast_f2b<<<dim3((MROWS*DMODEL/8 + 255)/256), blk, 0, stream>>>(ctx, ctxb, MROWS*DMODEL/8);
    castT_f2b<<<dim3(NQKV/32, DMODEL/32), blk, 0, stream>>>(Wq1, wq1t, DMODEL, NQKV);
    castT_f2b<<<dim3(NQKV/32, DMODEL/32), blk, 0, stream>>>(Wk1, wk1t, DMODEL, NQKV);
    castT_f2b<<<dim3(NQKV/32, DMODEL/32), blk, 0, stream>>>(Wv1, wv1t, DMODEL, NQKV);
    castT_f2b<<<dim3(DMODEL/32, NQKV/32), blk, 0, stream>>>(Wo1, wo1t, NQKV, DMODEL);
    castT_f2b<<<dim3(NQKV/32, DMODEL/32), blk, 0, stream>>>(Wq2, wq2t, DMODEL, NQKV);
    castT_f2b<<<dim3(NQKV/32, DMODEL/32), blk, 0, stream>>>(Wk2, wk2t, DMODEL, NQKV);
    castT_f2b<<<dim3(NQKV/32, DMODEL/32), blk, 0, stream>>>(Wv2, wv2t, DMODEL, NQKV);
    castT_f2b<<<dim3(DMODEL/32, NQKV/32), blk, 0, stream>>>(Wo2, wo2t, NQKV, DMODEL);
    castT_f2b<<<dim3(DFF/32, DMODEL/32), blk, 0, stream>>>(W1, w1t, DMODEL, DFF);
    castT_f2b<<<dim3(DMODEL/32, DFF/32), blk, 0, stream>>>(W2, w2t, DFF, DMODEL);

    // ---- causal self-attention + add&norm ----
    gemm_bf16<0,1><<<gQKV, blk, 0, stream>>>(xb, wq1t, bq1, nullptr, Qb, DMODEL, DMODEL, NQKV);
    gemm_bf16<0,1><<<gQKV, blk, 0, stream>>>(xb, wk1t, bk1, nullptr, Kb, DMODEL, DMODEL, NQKV);
    gemm_bf16<0,1><<<gQKV, blk, 0, stream>>>(xb, wv1t, bv1, nullptr, Vb, DMODEL, DMODEL, NQKV);
    vtrans<<<gVT, blk, 0, stream>>>(Vb, Vtg);
    attn_mfma<true><<<gAttn, blk, 0, stream>>>(Qb, Kb, Vtg, Qb);
    gemm_bf16<2,0><<<gOut, blk, 0, stream>>>(Qb, wo1t, bo1, x, Yf, NQKV, NQKV, DMODEL);
    ln_f32<<<gLN, blk, 0, stream>>>(Yf, g1, be1, X1f, X1b);
    // ---- cross-attention + add&norm ----
    gemm_bf16<0,1><<<gQKV, blk, 0, stream>>>(X1b,  wq2t, bq2, nullptr, Qb, DMODEL, DMODEL, NQKV);
    gemm_bf16<0,1><<<gQKV, blk, 0, stream>>>(ctxb, wk2t, bk2, nullptr, Kb, DMODEL, DMODEL, NQKV);
    gemm_bf16<0,1><<<gQKV, blk, 0, stream>>>(ctxb, wv2t, bv2, nullptr, Vb, DMODEL, DMODEL, NQKV);
    vtrans<<<gVT, blk, 0, stream>>>(Vb, Vtg);
    attn_mfma<false><<<gAttn, blk, 0, stream>>>(Qb, Kb, Vtg, Qb);
    gemm_bf16<2,0><<<gOut, blk, 0, stream>>>(Qb, wo2t, bo2, X1f, Yf, NQKV, NQKV, DMODEL);
    ln_f32<<<gLN, blk, 0, stream>>>(Yf, g2, be2, X2f, X2b);
    // ---- FFN + add&norm ----
    gemm_bf16<1,1><<<gF1,  blk, 0, stream>>>(X2b, w1t, b1, nullptr, Hb, DMODEL, DMODEL, DFF);
    gemm_bf16<2,0><<<gOut, blk, 0, stream>>>(Hb, w2t, b2, X2f, Yf, DFF, DFF, DMODEL);
    ln_f32<<<gLN, blk, 0, stream>>>(Yf, g3, be3, (float*)d_out, nullptr);
}

// Round 7
// 1359.275 us; speedup vs baseline: 4.6514x; 1.1808x over previous
//
#include <hip/hip_runtime.h>
#include <hip/hip_bf16.h>
#include <math.h>

#define BATCH   8
#define SEQ     1024
#define DMODEL  256
#define NHEADS  8
#define HDIM    256
#define NQKV    2048      /* NHEADS*HDIM */
#define DFF     1024
#define MROWS   (BATCH*SEQ)
#define LN_EPS  1e-3f
#define ATT_SCALE 0.0625f /* 1/sqrt(256) */

typedef unsigned int  uint;
typedef unsigned short ushort;
typedef __attribute__((ext_vector_type(8))) __bf16 bf16x8;
typedef __attribute__((ext_vector_type(4))) float   f32x4;
typedef __attribute__((ext_vector_type(4))) ushort  ushort4v;

__device__ __forceinline__ float b2f(ushort h) {
    union { uint u; float f; } v; v.u = ((uint)h) << 16; return v.f;
}
__device__ __forceinline__ ushort f2b(float f) {
    union { float f; uint u; } v; v.f = f;
    return (ushort)((v.u + 0x7FFFu + ((v.u >> 16) & 1u)) >> 16);
}
__device__ __forceinline__ uint pk2(float a, float b) {
    return (uint)f2b(a) | ((uint)f2b(b) << 16);
}

// ---------------------------------------------------------------------------
// bf16 MFMA GEMM: C[M,128-block] = A[M,K](bf16) @ Bt[N,K](bf16)^T + epilogue.
// EPI: 0 = +bias, 1 = +bias+ReLU, 2 = +bias+resid(fp32). OUTBF: 1 = bf16 C.
// 128x128 tile, BK=64, 4 waves each owning a 64x64 quadrant (4x4 of 16x16).
// LDS tiles XOR-swizzled (byte ^ ((row&7)<<4)): slot-uniform b128 access.
template<int EPI, int OUTBF>
__global__ __launch_bounds__(256, 2)
void gemm_bf16(const ushort* __restrict__ A, const ushort* __restrict__ Bt,
               const float* __restrict__ bias, const float* __restrict__ resid,
               void* __restrict__ Cv, int K, int lda, int ldc)
{
    __shared__ ushort As[128 * 64];
    __shared__ ushort Bs[128 * 64];
    const int t  = threadIdx.x;
    const int l  = t & 63;
    const int w  = t >> 6;
    const int wm = w >> 1, wn = w & 1;
    const int m0 = blockIdx.y * 128, n0 = blockIdx.x * 128;
    const int lg = l >> 4, lr = l & 15;

    f32x4 acc[4][4];
    #pragma unroll
    for (int i = 0; i < 4; i++)
        #pragma unroll
        for (int j = 0; j < 4; j++)
            acc[i][j] = (f32x4){0.f, 0.f, 0.f, 0.f};

    for (int k0 = 0; k0 < K; k0 += 64) {
        uint4 av[4], bv[4];
        #pragma unroll
        for (int j = 0; j < 4; j++) {
            const int chunk = t + j * 256;          // 0..1023
            const int row   = chunk >> 3;           // 0..127
            const int ce    = (chunk & 7) * 8;      // element col
            av[j] = *(const uint4*)&A [(size_t)(m0 + row) * lda + k0 + ce];
            bv[j] = *(const uint4*)&Bt[(size_t)(n0 + row) * K   + k0 + ce];
        }
        __syncthreads();   // previous iteration's reads done
        #pragma unroll
        for (int j = 0; j < 4; j++) {
            const int chunk = t + j * 256;
            const int row   = chunk >> 3;
            const int woff  = (chunk * 16) ^ ((row & 7) << 4);
            *(uint4*)((char*)As + woff) = av[j];
            *(uint4*)((char*)Bs + woff) = bv[j];
        }
        __syncthreads();   // tiles visible
        #pragma unroll
        for (int c = 0; c < 2; c++) {
            bf16x8 af[4], bf[4];
            #pragma unroll
            for (int i = 0; i < 4; i++) {
                const int rowA = wm * 64 + i * 16 + lr;
                const int offA = (rowA * 128 + c * 64 + lg * 16) ^ ((rowA & 7) << 4);
                af[i] = *(const bf16x8*)((const char*)As + offA);
                const int rowB = wn * 64 + i * 16 + lr;
                const int offB = (rowB * 128 + c * 64 + lg * 16) ^ ((rowB & 7) << 4);
                bf[i] = *(const bf16x8*)((const char*)Bs + offB);
            }
            #pragma unroll
            for (int mi = 0; mi < 4; mi++)
                #pragma unroll
                for (int ni = 0; ni < 4; ni++)
                    acc[mi][ni] = __builtin_amdgcn_mfma_f32_16x16x32_bf16(
                        af[mi], bf[ni], acc[mi][ni], 0, 0, 0);
        }
    }

    // epilogue: C row = m0 + wm*64 + mi*16 + lg*4 + r ; col = n0 + wn*64 + ni*16 + lr
    #pragma unroll
    for (int ni = 0; ni < 4; ni++) {
        const int col = n0 + wn * 64 + ni * 16 + lr;
        const float bb = bias[col];
        #pragma unroll
        for (int mi = 0; mi < 4; mi++) {
            #pragma unroll
            for (int r = 0; r < 4; r++) {
                const int row = m0 + wm * 64 + mi * 16 + lg * 4 + r;
                float v = acc[mi][ni][r] + bb;
                if (EPI == 1) v = fmaxf(v, 0.f);
                if (EPI == 2) v += resid[(size_t)row * ldc + col];
                if (OUTBF) ((ushort*)Cv)[(size_t)row * ldc + col] = f2b(v);
                else       ((float*) Cv)[(size_t)row * ldc + col] = v;
            }
        }
    }
}

// ---------------------------------------------------------------------------
// V transpose: V[b,s, h*256+d] (bf16) -> Vt[(b*8+h)*256 + d][s] (bf16).
// 64x64 tiles through LDS; coalesced on both sides.
__global__ __launch_bounds__(256)
void vtrans(const ushort* __restrict__ V, ushort* __restrict__ Vt)
{
    __shared__ ushort tl[64][72];
    const int s0 = blockIdx.x * 64;
    const int d0 = blockIdx.y * 64;
    const int bh = blockIdx.z;
    const int b  = bh >> 3, h = bh & 7;
    const int t  = threadIdx.x;
    #pragma unroll
    for (int j = 0; j < 2; j++) {
        const int chunk = t + j * 256;
        const int row = chunk >> 3, c8 = (chunk & 7) * 8;
        *(uint4*)&tl[row][c8] =
            *(const uint4*)&V[((size_t)(b * SEQ + s0 + row)) * NQKV + h * HDIM + d0 + c8];
    }
    __syncthreads();
    #pragma unroll
    for (int j = 0; j < 2; j++) {
        const int chunk = t + j * 256;
        const int dr = chunk >> 3, s8 = (chunk & 7) * 8;
        ushort tmp[8] __attribute__((aligned(16)));
        #pragma unroll
        for (int i = 0; i < 8; i++) tmp[i] = tl[s8 + i][dr];
        *(uint4*)&Vt[((size_t)(bh * HDIM + d0 + dr)) * SEQ + s0 + s8] = *(const uint4*)tmp;
    }
}

// ---------------------------------------------------------------------------
// MFMA flash attention v2: bf16 in/out, fp32 softmax state.
// Q,K,O: [B,S,NHEADS*HDIM] bf16. Vt: [(b*8+h)*256 + d][s] bf16.
// Block = (b,h) x 64 q-rows; 4 waves, each owns 16 q-rows.
// v2 changes: (1) XCD-chunked blockIdx swizzle so all 16 q-blocks of a (b,h)
// share one XCD's L2; (2) K/V global loads for tile t+1 issued before tile t's
// compute (register prefetch, T14) so HBM latency hides under MFMA/softmax;
// (3) launch_bounds(256,1) to give the allocator room (no spill).
template<bool CAUSAL>
__global__ __launch_bounds__(256, 1)
void attn_mfma(const ushort* __restrict__ Q, const ushort* __restrict__ K,
               const ushort* __restrict__ Vt, ushort* __restrict__ O)
{
    __shared__ __align__(16) char lds[37888];
    // [0,16384):      K tile  [32 s][512B] xor-swizzled ((row&7)<<4)
    // [16384,32768):  Vt tile [256 d][64B] xor-swizzled ((row&3)<<4)
    // [32768,37888):  P per wave: [16 q][80B] (stride 40 ushorts)
    // Q staged once into [0,32768) before the main loop.

    const int t  = threadIdx.x;
    const int w  = t >> 6, l = t & 63;
    const int lg = l >> 4, lr = l & 15;
    // XCD-chunked bijective swizzle over the 1024-block grid (1024 % 8 == 0)
    const int orig = blockIdx.x + (blockIdx.y << 4) + (blockIdx.z << 7);
    const int lin  = ((orig & 7) << 7) + (orig >> 3);
    const int qt0  = (lin & 15) << 6;
    const int h    = (lin >> 4) & 7;
    const int b    = lin >> 7;

    // ---- stage Q (64 rows x 512B) ----
    const size_t qgbase = ((size_t)(b * SEQ + qt0)) * NQKV + (size_t)h * HDIM;
    #pragma unroll
    for (int j = 0; j < 8; j++) {
        const int chunk = t + j * 256;
        const int row = chunk >> 5, slot = chunk & 31;
        const uint4 v = *(const uint4*)&Q[qgbase + (size_t)row * NQKV + slot * 8];
        *(uint4*)(lds + row * 512 + ((slot * 16) ^ ((row & 7) << 4))) = v;
    }

    const size_t kgbase = (size_t)b * SEQ * NQKV + (size_t)h * HDIM;
    const size_t vgbase = ((size_t)(b * NHEADS + h)) * HDIM * SEQ;
    const int ntiles = CAUSAL ? (qt0 / 32 + 2) : (SEQ / 32);

    // ---- prefetch tile 0 into registers ----
    uint4 kv[4], vv[4];
    #pragma unroll
    for (int j = 0; j < 4; j++) {
        const int chunk = t + j * 256;
        const int krow = chunk >> 5, kslot = chunk & 31;
        kv[j] = *(const uint4*)&K[kgbase + (size_t)krow * NQKV + kslot * 8];
        const int vrow = chunk >> 2, vslot = chunk & 3;
        vv[j] = *(const uint4*)&Vt[vgbase + (size_t)vrow * SEQ + vslot * 8];
    }

    __syncthreads();   // Q tile visible
    bf16x8 qa[8];
    {
        const int qrow = w * 16 + lr;
        const int sw = (qrow & 7) << 4;
        #pragma unroll
        for (int ks = 0; ks < 8; ks++)
            qa[ks] = *(const bf16x8*)(lds + qrow * 512 + ((lg * 16 + ks * 64) ^ sw));
    }

    f32x4 oacc[16];
    #pragma unroll
    for (int i = 0; i < 16; i++) oacc[i] = (f32x4){0.f, 0.f, 0.f, 0.f};
    float m_[4], l_[4];
    #pragma unroll
    for (int r = 0; r < 4; r++) { m_[r] = -INFINITY; l_[r] = 0.f; }

    ushort* Pw = (ushort*)(lds + 32768 + w * 1280);

    for (int tile = 0; tile < ntiles; tile++) {
        const int s0 = tile * 32;
        __syncthreads();   // prev tile's LDS reads (or Q-frag pull) done
        #pragma unroll
        for (int j = 0; j < 4; j++) {
            const int chunk = t + j * 256;
            const int krow = chunk >> 5, kslot = chunk & 31;
            *(uint4*)(lds + krow * 512 + ((kslot * 16) ^ ((krow & 7) << 4))) = kv[j];
            const int vrow = chunk >> 2, vslot = chunk & 3;
            *(uint4*)(lds + 16384 + vrow * 64 + ((vslot * 16) ^ ((vrow & 3) << 4))) = vv[j];
        }
        __syncthreads();   // tile visible

        // ---- issue next tile's global loads (hide HBM under compute) ----
        if (tile + 1 < ntiles) {
            const int s0n = s0 + 32;
            #pragma unroll
            for (int j = 0; j < 4; j++) {
                const int chunk = t + j * 256;
                const int krow = chunk >> 5, kslot = chunk & 31;
                kv[j] = *(const uint4*)&K[kgbase + (size_t)(s0n + krow) * NQKV + kslot * 8];
                const int vrow = chunk >> 2, vslot = chunk & 3;
                vv[j] = *(const uint4*)&Vt[vgbase + (size_t)vrow * SEQ + s0n + vslot * 8];
            }
        }

        // ---- S = Q K^T (2 s-tiles x 8 k-steps) ----
        f32x4 sacc[2];
        sacc[0] = (f32x4){0.f, 0.f, 0.f, 0.f};
        sacc[1] = (f32x4){0.f, 0.f, 0.f, 0.f};
        #pragma unroll
        for (int ks = 0; ks < 8; ks++) {
            #pragma unroll
            for (int st = 0; st < 2; st++) {
                const int srow = st * 16 + lr;
                const bf16x8 kb = *(const bf16x8*)(lds + srow * 512 +
                                   ((lg * 16 + ks * 64) ^ ((srow & 7) << 4)));
                sacc[st] = __builtin_amdgcn_mfma_f32_16x16x32_bf16(qa[ks], kb, sacc[st], 0, 0, 0);
            }
        }

        // ---- online softmax (rows q_w = lg*4+r, 16-lane groups) ----
        const bool maskq = CAUSAL && (s0 + 31 > qt0 + w * 16);
        float e0[4], e1[4], corr[4];
        #pragma unroll
        for (int r = 0; r < 4; r++) {
            float p0 = sacc[0][r] * ATT_SCALE;
            float p1 = sacc[1][r] * ATT_SCALE;
            if (maskq) {
                const int qg = qt0 + w * 16 + lg * 4 + r;
                if (s0 + lr > qg)      p0 = -1e9f;
                if (s0 + 16 + lr > qg) p1 = -1e9f;
            }
            float mx = fmaxf(p0, p1);
            mx = fmaxf(mx, __shfl_xor(mx, 1));
            mx = fmaxf(mx, __shfl_xor(mx, 2));
            mx = fmaxf(mx, __shfl_xor(mx, 4));
            mx = fmaxf(mx, __shfl_xor(mx, 8));
            const float newm = fmaxf(m_[r], mx);
            corr[r] = __expf(m_[r] - newm);
            m_[r] = newm;
            e0[r] = __expf(p0 - newm);
            e1[r] = __expf(p1 - newm);
            float es = e0[r] + e1[r];
            es += __shfl_xor(es, 1);
            es += __shfl_xor(es, 2);
            es += __shfl_xor(es, 4);
            es += __shfl_xor(es, 8);
            l_[r] = l_[r] * corr[r] + es;
        }
        // write P (bf16) to per-wave LDS, rescale O accumulator
        #pragma unroll
        for (int r = 0; r < 4; r++) {
            Pw[(lg * 4 + r) * 40 + lr]      = f2b(e0[r]);
            Pw[(lg * 4 + r) * 40 + 16 + lr] = f2b(e1[r]);
        }
        #pragma unroll
        for (int dt = 0; dt < 16; dt++) {
            oacc[dt][0] *= corr[0]; oacc[dt][1] *= corr[1];
            oacc[dt][2] *= corr[2]; oacc[dt][3] *= corr[3];
        }

        // ---- O += P V (A-frag from P LDS, B-frags from Vt LDS) ----
        const bf16x8 pa = *(const bf16x8*)((const char*)Pw + lr * 80 + lg * 16);
        #pragma unroll
        for (int dt = 0; dt < 16; dt++) {
            const int vrow = dt * 16 + lr;
            const bf16x8 vb = *(const bf16x8*)(lds + 16384 + vrow * 64 +
                               ((lg * 16) ^ ((vrow & 3) << 4)));
            oacc[dt] = __builtin_amdgcn_mfma_f32_16x16x32_bf16(pa, vb, oacc[dt], 0, 0, 0);
        }
    }

    // ---- epilogue: O[q][d] = oacc / l ----
    float inv[4];
    #pragma unroll
    for (int r = 0; r < 4; r++) inv[r] = 1.f / l_[r];
    const size_t obase = ((size_t)(b * SEQ + qt0 + w * 16)) * NQKV + (size_t)h * HDIM;
    #pragma unroll
    for (int dt = 0; dt < 16; dt++) {
        #pragma unroll
        for (int r = 0; r < 4; r++) {
            O[obase + (size_t)(lg * 4 + r) * NQKV + dt * 16 + lr] =
                f2b(oacc[dt][r] * inv[r]);
        }
    }
}

// ---------------------------------------------------------------------------
// LayerNorm over last dim (256). One wave per row, 4 rows per block.
// Optional bf16 dual write (Yb may be null).
__global__ __launch_bounds__(256)
void ln_f32(const float* __restrict__ X, const float* __restrict__ gamma,
            const float* __restrict__ beta, float* __restrict__ Y,
            ushort* __restrict__ Yb)
{
    const int lane = threadIdx.x & 63;
    const int row  = blockIdx.x * 4 + (threadIdx.x >> 6);
    const float4 v = *(const float4*)&X[(size_t)row * DMODEL + lane * 4];
    float s = v.x + v.y + v.z + v.w;
    #pragma unroll
    for (int o = 1; o < 64; o <<= 1) s += __shfl_xor(s, o);
    const float mu = s * (1.f / 256.f);
    const float dx = v.x - mu, dy = v.y - mu, dz = v.z - mu, dw = v.w - mu;
    float ss = dx*dx + dy*dy + dz*dz + dw*dw;
    #pragma unroll
    for (int o = 1; o < 64; o <<= 1) ss += __shfl_xor(ss, o);
    const float rstd = rsqrtf(ss * (1.f / 256.f) + LN_EPS);
    const float4 gv = *(const float4*)&gamma[lane * 4];
    const float4 bv = *(const float4*)&beta[lane * 4];
    float4 out;
    out.x = dx * rstd * gv.x + bv.x;
    out.y = dy * rstd * gv.y + bv.y;
    out.z = dz * rstd * gv.z + bv.z;
    out.w = dw * rstd * gv.w + bv.w;
    *(float4*)&Y[(size_t)row * DMODEL + lane * 4] = out;
    if (Yb) {
        uint2 p; p.x = pk2(out.x, out.y); p.y = pk2(out.z, out.w);
        *(uint2*)&Yb[(size_t)row * DMODEL + lane * 4] = p;
    }
}

// ---------------------------------------------------------------------------
// Elementwise fp32 -> bf16 cast (n8 = elements/8).
__global__ __launch_bounds__(256)
void cast_f2b(const float* __restrict__ X, ushort* __restrict__ Y, int n8)
{
    const int i = blockIdx.x * 256 + threadIdx.x;
    if (i < n8) {
        const float4 a = *(const float4*)&X[(size_t)i * 8];
        const float4 b = *(const float4*)&X[(size_t)i * 8 + 4];
        uint4 o;
        o.x = pk2(a.x, a.y); o.y = pk2(a.z, a.w);
        o.z = pk2(b.x, b.y); o.w = pk2(b.z, b.w);
        *(uint4*)&Y[(size_t)i * 8] = o;
    }
}

// Transpose-cast: W[K][N] fp32 -> Wt[N][K] bf16. Grid (N/32, K/32), block 256.
__global__ __launch_bounds__(256)
void castT_f2b(const float* __restrict__ W, ushort* __restrict__ Wt, int Kd, int Nd)
{
    __shared__ float tile[32][33];
    const int k0 = blockIdx.y * 32, n0 = blockIdx.x * 32;
    const int r  = threadIdx.x >> 3;
    const int c4 = (threadIdx.x & 7) * 4;
    const float4 v = *(const float4*)&W[(size_t)(k0 + r) * Nd + n0 + c4];
    tile[r][c4+0] = v.x; tile[r][c4+1] = v.y; tile[r][c4+2] = v.z; tile[r][c4+3] = v.w;
    __syncthreads();
    ushort4v ov = { f2b(tile[c4+0][r]), f2b(tile[c4+1][r]),
                    f2b(tile[c4+2][r]), f2b(tile[c4+3][r]) };
    *(ushort4v*)&Wt[(size_t)(n0 + r) * Kd + k0 + c4] = ov;
}

// ---------------------------------------------------------------------------
extern "C" void kernel_launch(void* const* d_in, const int* in_sizes, int n_in,
                              void* d_out, int out_size, void* d_ws, size_t ws_size,
                              hipStream_t stream)
{
    const float* x    = (const float*)d_in[0];
    const float* ctx  = (const float*)d_in[1];
    const float* Wq1  = (const float*)d_in[2];
    const float* bq1  = (const float*)d_in[3];
    const float* Wk1  = (const float*)d_in[4];
    const float* bk1  = (const float*)d_in[5];
    const float* Wv1  = (const float*)d_in[6];
    const float* bv1  = (const float*)d_in[7];
    const float* Wo1  = (const float*)d_in[8];
    const float* bo1  = (const float*)d_in[9];
    const float* g1   = (const float*)d_in[10];
    const float* be1  = (const float*)d_in[11];
    const float* Wq2  = (const float*)d_in[12];
    const float* bq2  = (const float*)d_in[13];
    const float* Wk2  = (const float*)d_in[14];
    const float* bk2  = (const float*)d_in[15];
    const float* Wv2  = (const float*)d_in[16];
    const float* bv2  = (const float*)d_in[17];
    const float* Wo2  = (const float*)d_in[18];
    const float* bo2  = (const float*)d_in[19];
    const float* g2   = (const float*)d_in[20];
    const float* be2  = (const float*)d_in[21];
    const float* W1   = (const float*)d_in[22];
    const float* b1   = (const float*)d_in[23];
    const float* W2   = (const float*)d_in[24];
    const float* b2   = (const float*)d_in[25];
    const float* g3   = (const float*)d_in[26];
    const float* be3  = (const float*)d_in[27];
    (void)in_sizes; (void)n_in; (void)out_size; (void)ws_size;

    char* base = (char*)d_ws;
    const size_t MB1 = 1024 * 1024;
    ushort* Qb   = (ushort*)(base + 0 * MB1);     // 32 MiB (O aliases)
    ushort* Kb   = (ushort*)(base + 32 * MB1);    // 32 MiB
    ushort* Vb   = (ushort*)(base + 64 * MB1);    // 32 MiB
    float*  Yf   = (float*) (base + 96 * MB1);    // 8 MiB
    float*  X1f  = (float*) (base + 104 * MB1);   // 8 MiB
    float*  X2f  = (float*) (base + 112 * MB1);   // 8 MiB
    ushort* xb   = (ushort*)(base + 120 * MB1);   // 4 MiB
    ushort* ctxb = (ushort*)(base + 124 * MB1);   // 4 MiB
    ushort* X1b  = (ushort*)(base + 128 * MB1);   // 4 MiB
    ushort* X2b  = (ushort*)(base + 132 * MB1);   // 4 MiB
    ushort* wq1t = (ushort*)(base + 136 * MB1);   // 1 MiB each
    ushort* wk1t = (ushort*)(base + 137 * MB1);
    ushort* wv1t = (ushort*)(base + 138 * MB1);
    ushort* wo1t = (ushort*)(base + 139 * MB1);
    ushort* wq2t = (ushort*)(base + 140 * MB1);
    ushort* wk2t = (ushort*)(base + 141 * MB1);
    ushort* wv2t = (ushort*)(base + 142 * MB1);
    ushort* wo2t = (ushort*)(base + 143 * MB1);
    ushort* w1t  = (ushort*)(base + 144 * MB1);   // 0.5 MiB
    ushort* w2t  = (ushort*)(base + 144 * MB1 + 512 * 1024);
    ushort* Hb   = (ushort*)(base + 145 * MB1);   // 16 MiB (ends 161)
    ushort* Vtg  = (ushort*)(base + 161 * MB1);   // 32 MiB (ends 193)

    const dim3 blk(256);
    const dim3 gQKV(NQKV/128, MROWS/128);   // (16,64)
    const dim3 gOut(DMODEL/128, MROWS/128); // (2,64)
    const dim3 gF1(DFF/128, MROWS/128);     // (8,64)
    const dim3 gAttn(SEQ/64, NHEADS, BATCH);
    const dim3 gVT(SEQ/64, HDIM/64, BATCH*NHEADS);
    const dim3 gLN(MROWS/4);

    // ---- casts ----
    cast_f2b<<<dim3((MROWS*DMODEL/8 + 255)/256), blk, 0, stream>>>(x,   xb,   MROWS*DMODEL/8);
    cast_f2b<<<dim3((MROWS*DMODEL/8 + 255)/256), blk, 0, stream>>>(ctx, ctxb, MROWS*DMODEL/8);
    castT_f2b<<<dim3(NQKV/32, DMODEL/32), blk, 0, stream>>>(Wq1, wq1t, DMODEL, NQKV);
    castT_f2b<<<dim3(NQKV/32, DMODEL/32), blk, 0, stream>>>(Wk1, wk1t, DMODEL, NQKV);
    castT_f2b<<<dim3(NQKV/32, DMODEL/32), blk, 0, stream>>>(Wv1, wv1t, DMODEL, NQKV);
    castT_f2b<<<dim3(DMODEL/32, NQKV/32), blk, 0, stream>>>(Wo1, wo1t, NQKV, DMODEL);
    castT_f2b<<<dim3(NQKV/32, DMODEL/32), blk, 0, stream>>>(Wq2, wq2t, DMODEL, NQKV);
    castT_f2b<<<dim3(NQKV/32, DMODEL/32), blk, 0, stream>>>(Wk2, wk2t, DMODEL, NQKV);
    castT_f2b<<<dim3(NQKV/32, DMODEL/32), blk, 0, stream>>>(Wv2, wv2t, DMODEL, NQKV);
    castT_f2b<<<dim3(DMODEL/32, NQKV/32), blk, 0, stream>>>(Wo2, wo2t, NQKV, DMODEL);
    castT_f2b<<<dim3(DFF/32, DMODEL/32), blk, 0, stream>>>(W1, w1t, DMODEL, DFF);
    castT_f2b<<<dim3(DMODEL/32, DFF/32), blk, 0, stream>>>(W2, w2t, DFF, DMODEL);

    // ---- causal self-attention + add&norm ----
    gemm_bf16<0,1><<<gQKV, blk, 0, stream>>>(xb, wq1t, bq1, nullptr, Qb, DMODEL, DMODEL, NQKV);
    gemm_bf16<0,1><<<gQKV, blk, 0, stream>>>(xb, wk1t, bk1, nullptr, Kb, DMODEL, DMODEL, NQKV);
    gemm_bf16<0,1><<<gQKV, blk, 0, stream>>>(xb, wv1t, bv1, nullptr, Vb, DMODEL, DMODEL, NQKV);
    vtrans<<<gVT, blk, 0, stream>>>(Vb, Vtg);
    attn_mfma<true><<<gAttn, blk, 0, stream>>>(Qb, Kb, Vtg, Qb);
    gemm_bf16<2,0><<<gOut, blk, 0, stream>>>(Qb, wo1t, bo1, x, Yf, NQKV, NQKV, DMODEL);
    ln_f32<<<gLN, blk, 0, stream>>>(Yf, g1, be1, X1f, X1b);
    // ---- cross-attention + add&norm ----
    gemm_bf16<0,1><<<gQKV, blk, 0, stream>>>(X1b,  wq2t, bq2, nullptr, Qb, DMODEL, DMODEL, NQKV);
    gemm_bf16<0,1><<<gQKV, blk, 0, stream>>>(ctxb, wk2t, bk2, nullptr, Kb, DMODEL, DMODEL, NQKV);
    gemm_bf16<0,1><<<gQKV, blk, 0, stream>>>(ctxb, wv2t, bv2, nullptr, Vb, DMODEL, DMODEL, NQKV);
    vtrans<<<gVT, blk, 0, stream>>>(Vb, Vtg);
    attn_mfma<false><<<gAttn, blk, 0, stream>>>(Qb, Kb, Vtg, Qb);
    gemm_bf16<2,0><<<gOut, blk, 0, stream>>>(Qb, wo2t, bo2, X1f, Yf, NQKV, NQKV, DMODEL);
    ln_f32<<<gLN, blk, 0, stream>>>(Yf, g2, be2, X2f, X2b);
    // ---- FFN + add&norm ----
    gemm_bf16<1,1><<<gF1,  blk, 0, stream>>>(X2b, w1t, b1, nullptr, Hb, DMODEL, DMODEL, DFF);
    gemm_bf16<2,0><<<gOut, blk, 0, stream>>>(Hb, w2t, b2, X2f, Yf, DFF, DFF, DMODEL);
    ln_f32<<<gLN, blk, 0, stream>>>(Yf, g3, be3, (float*)d_out, nullptr);
}